// Round 2
// baseline (5965.574 us; speedup 1.0000x reference)
//
#include <hip/hip_runtime.h>

#define NXI 384
#define NG  (NXI*NXI)          // 147456 elements per system
#define NSYS 8
#define BPS 32                 // blocks per system
#define NBLK (NSYS*BPS)        // 256 blocks
#define NTHR 256
#define TPS (BPS*NTHR)         // 8192 threads per system
#define EPT (NG/TPS)           // 18 elements per thread

// thr = EPS*NX*NY = 1e-9*147456
#define THRC 1.47456e-4f

__device__ __forceinline__ double wave_red(double v) {
#pragma unroll
  for (int off = 32; off > 0; off >>= 1) v += __shfl_down(v, off, 64);
  return v;
}

// ---- hand-rolled grid barrier: monotonic counter, phased wait ----
// All call sites are grid-uniform. Counter region must be zeroed before launch
// (done with hipMemsetAsync in kernel_launch — capture-legal).
__device__ __forceinline__ void grid_bar(unsigned* bar, unsigned* phase) {
  __syncthreads();
  if (threadIdx.x == 0) {
    __threadfence();  // agent-scope release of this block's prior writes
    const unsigned ph = ++(*phase);
    __hip_atomic_fetch_add(bar, 1u, __ATOMIC_RELEASE, __HIP_MEMORY_SCOPE_AGENT);
    while (__hip_atomic_load(bar, __ATOMIC_ACQUIRE, __HIP_MEMORY_SCOPE_AGENT) < ph * NBLK) {
      __builtin_amdgcn_s_sleep(1);
    }
    __threadfence();  // acquire: invalidate stale cached lines before block proceeds
  } else {
    ++(*phase);
  }
  __syncthreads();
}

// Block-reduce 3 doubles and store to slot channels [chan0..chan0+2][sys][bs].
__device__ __forceinline__ void bred_store(double v0, double v1, double v2,
                                           double* __restrict__ slots, int chan0,
                                           int sys, int bs, int tid) {
  __shared__ double sred[4][3];
  const int wid = tid >> 6, lane = tid & 63;
  const double w0 = wave_red(v0);
  const double w1 = wave_red(v1);
  const double w2 = wave_red(v2);
  if (lane == 0) { sred[wid][0] = w0; sred[wid][1] = w1; sred[wid][2] = w2; }
  __syncthreads();
  if (tid == 0) {
#pragma unroll
    for (int q = 0; q < 3; q++) {
      const double a = sred[0][q] + sred[1][q] + sred[2][q] + sred[3][q];
      slots[(size_t)(chan0 + q) * NBLK + sys * BPS + bs] = a;
    }
  }
  __syncthreads();
}

// Deterministic sum of the 32 per-block partials of one channel/system.
__device__ __forceinline__ double slot_sum(const double* __restrict__ slots, int chan, int sys) {
  const double* p = slots + (size_t)chan * NBLK + sys * BPS;
  double a = 0.0;
#pragma unroll
  for (int b = 0; b < BPS; b++) a += p[b];
  return a;
}

// fro() guard semantics from the reference: sqrt(sq) if sq>0 else 0
__device__ __forceinline__ float froguard(double sq) {
  return sq > 0.0 ? (float)sqrt(sq) : 0.0f;
}

// 5-point stencil apply with symmetric (edge-clamp) boundary. uc = u[idx].
__device__ __forceinline__ float applyA(const float* __restrict__ u, float uc, int idx, int i, int j,
                                        const float* __restrict__ cboo, const float* __restrict__ cbmo,
                                        const float* __restrict__ cbom, const float* __restrict__ cbop,
                                        const float* __restrict__ cbpo) {
  const float um = (i == 0)       ? uc : u[idx - NXI];
  const float ud = (i == NXI - 1) ? uc : u[idx + NXI];
  const float ul = (j == 0)       ? uc : u[idx - 1];
  const float ur = (j == NXI - 1) ? uc : u[idx + 1];
  // same association order as the reference expression
  return cboo[idx] * uc + cbmo[idx] * um + cbom[idx] * ul + cbop[idx] * ur + cbpo[idx] * ud;
}

__global__ __launch_bounds__(NTHR, 1) void bicg_kernel(
    const float* __restrict__ V, const float* __restrict__ M1, const float* __restrict__ M2,
    float* __restrict__ xout, float* __restrict__ wsf) {
  const int blk = blockIdx.x;
  const int sys = blk & (NSYS - 1);   // blockIdx%8 -> each system pinned to one XCD
  const int bs  = blk >> 3;
  const int tid = threadIdx.x;
  const int ts  = bs * NTHR + tid;    // thread-in-system [0,8192)

  // ---- workspace layout (first 32 KB = control, then 7 vector fields) ----
  unsigned* bar = (unsigned*)wsf;                    // [0..31]: barrier counter line (memset to 0)
  double* slots = (double*)(wsf + 32);               // 15 chans * 256 doubles
  float* g_rabs = (float*)(slots + 15 * NBLK);       // 8 floats
  int*   g_c4   = (int*)(g_rabs + NSYS);             // 8 ints
  float* base   = wsf + 8192;                        // 32 KB offset
  float* cboo = base + 0ull * NSYS * NG;
  float* cbmo = base + 1ull * NSYS * NG;
  float* cbom = base + 2ull * NSYS * NG;
  float* cbop = base + 3ull * NSYS * NG;
  float* cbpo = base + 4ull * NSYS * NG;
  float* pva  = base + 5ull * NSYS * NG;
  float* sva  = base + 6ull * NSYS * NG;

  unsigned bphase = 0;

  const size_t so = (size_t)sys * NG;
  const float* Vb  = V  + so;
  const float* M1b = M1 + so;
  const float* M2b = M2 + so;
  float* boos = cboo + so; float* bmos = cbmo + so; float* boms = cbom + so;
  float* bops = cbop + so; float* bpos = cbpo + so;
  float* xs = xout + so;   // x lives directly in d_out (interior layout matches output)
  float* ps = pva + so;
  float* ss = sva + so;

  // ---------- Phase 0: stencil coefficients + V-mean partial ----------
  // Vt(a,b) = V[scl(b)*384 + scl(a)] + 1 (transpose + symmetric pad), scl(a)=clamp(a-1,0,383)
  double vsum = 0.0;
#pragma unroll
  for (int k = 0; k < EPT; k++) {
    const int idx = ts + k * TPS;
    vsum += (double)Vb[idx];
    const int i = (int)((unsigned)idx / (unsigned)NXI);
    const int j = idx - i * NXI;
    const int a0 = (i - 1 < 0) ? 0 : i - 1;             // scl(i)
    const int a1 = i;                                   // scl(i+1)
    const int a2 = (i + 1 > NXI - 1) ? NXI - 1 : i + 1; // scl(i+2)
    const int b0 = (j - 1 < 0) ? 0 : j - 1;             // scl(j)
    const int b1 = j;                                   // scl(j+1)
    const int b2 = (j + 1 > NXI - 1) ? NXI - 1 : j + 1; // scl(j+2)
    const float vc = Vb[b1 * NXI + a1] + 1.0f;  // Vt(i+1,j+1)
    const float vu = Vb[b1 * NXI + a0] + 1.0f;  // Vt(i,  j+1)
    const float vd = Vb[b1 * NXI + a2] + 1.0f;  // Vt(i+2,j+1)
    const float vl = Vb[b0 * NXI + a1] + 1.0f;  // Vt(i+1,j)
    const float vr = Vb[b2 * NXI + a1] + 1.0f;  // Vt(i+1,j+2)
    const float D1A = M1b[b1 * NXI + a1] * ((vd - vc) / (0.5f * (vd + vc))); // d1(i+1,j+1)
    const float D1B = M1b[b1 * NXI + a0] * ((vc - vu) / (0.5f * (vc + vu))); // d1(i,  j+1)
    const float D2A = M2b[b1 * NXI + a1] * ((vr - vc) / (0.5f * (vr + vc))); // d2(i+1,j+1)
    const float D2B = M2b[b0 * NXI + a1] * ((vc - vl) / (0.5f * (vc + vl))); // d2(i+1,j)
    boos[idx] = 41.0f - 5.0f * (D1B - D1A) - 5.0f * (D2B - D2A);
    bpos[idx] = -10.0f + 5.0f * D1A;
    bmos[idx] = -10.0f - 5.0f * D1B;
    bops[idx] = -10.0f + 5.0f * D2A;
    boms[idx] = -10.0f - 5.0f * D2B;
  }
  bred_store(vsum, 0.0, 0.0, slots, 0, sys, bs, tid);
  grid_bar(bar, &bphase);  // S0a

  // ---------- Phase 0b: x=mb; p=r=r0=b-Ax (x const -> no neighbor reads) ----------
  const float mb = (float)(slot_sum(slots, 0, sys) / (double)NG) + 1.0f;  // mean(V)+OFFSET
  float preg[EPT], rreg[EPT], r0reg[EPT], vreg[EPT], treg[EPT];
  double r0sq = 0.0;
#pragma unroll
  for (int k = 0; k < EPT; k++) {
    const int idx = ts + k * TPS;
    const float ax = boos[idx] * mb + bmos[idx] * mb + boms[idx] * mb + bops[idx] * mb + bpos[idx] * mb;
    const float pn = mb - ax;
    xs[idx] = mb;
    ps[idx] = pn;
    preg[k] = pn; rreg[k] = pn; r0reg[k] = pn;
    r0sq += (double)pn * (double)pn;
  }
  bred_store(r0sq, 0.0, 0.0, slots, 6, sys, bs, tid);
  grid_bar(bar, &bphase);  // S0b
  float r0_abs = froguard(slot_sum(slots, 6, sys));
  float r_abs = r0_abs;
  if (ts == 0) g_rabs[sys] = r_abs;
  grid_bar(bar, &bphase);  // S0c (publish g_rabs for the first loop-top read)

  float alpha = 0.f, omega = 0.f, rho = 0.f;
  volatile float* vrabs = g_rabs;
  volatile int*   vc4   = g_c4;

  for (int it = 0; it < 30; ++it) {
    // global early-exit: uniform decision from published g_rabs
    bool anyact = false;
#pragma unroll
    for (int s2 = 0; s2 < NSYS; s2++) anyact = anyact || (vrabs[s2] > THRC);
    if (!anyact) break;

    const bool CONV = (r_abs > THRC);
    // ---- Phase 1: v = A p ; reduce sigma=<v,r0>, vabs2=<v,v>, rho=<r,r0>
    if (CONV) {
      double psig = 0, pvab = 0, prho = 0;
#pragma unroll
      for (int k = 0; k < EPT; k++) {
        const int idx = ts + k * TPS;
        const int i = (int)((unsigned)idx / (unsigned)NXI);
        const int j = idx - i * NXI;
        const float vv = applyA(ps, preg[k], idx, i, j, boos, bmos, boms, bops, bpos);
        vreg[k] = vv;
        psig += (double)vv * (double)r0reg[k];
        pvab += (double)vv * (double)vv;
        prho += (double)rreg[k] * (double)r0reg[k];
      }
      bred_store(psig, pvab, prho, slots, 3, sys, bs, tid);
    }
    grid_bar(bar, &bphase);  // S1

    // ---- Phase 2: restart (RES) or s = r - alpha*v
    bool RES = false, C4 = false;
    if (CONV) {
      const float sigma = (float)slot_sum(slots, 3, sys);
      const float v_abs = froguard(slot_sum(slots, 4, sys));
      rho = (float)slot_sum(slots, 5, sys);
      RES = (sigma <= 1e-9f * v_abs * r0_abs);
      double pacc = 0;
      if (RES) {
        // p = r = r0 = b - A x ; reduce <p,p>
#pragma unroll
        for (int k = 0; k < EPT; k++) {
          const int idx = ts + k * TPS;
          const int i = (int)((unsigned)idx / (unsigned)NXI);
          const int j = idx - i * NXI;
          const float ax = applyA(xs, xs[idx], idx, i, j, boos, bmos, boms, bops, bpos);
          const float pn = mb - ax;
          ps[idx] = pn;
          preg[k] = pn; rreg[k] = pn; r0reg[k] = pn;
          pacc += (double)pn * (double)pn;
        }
      } else {
        alpha = rho / sigma;
#pragma unroll
        for (int k = 0; k < EPT; k++) {
          const int idx = ts + k * TPS;
          const float sv = rreg[k] - alpha * vreg[k];
          ss[idx] = sv;
          pacc += (double)sv * (double)sv;
        }
      }
      bred_store(pacc, 0.0, 0.0, slots, 6, sys, bs, tid);
    }
    grid_bar(bar, &bphase);  // S2

    // ---- Phase 3: finalize restart / C3 terminal update / t = A s
    if (CONV) {
      if (RES) {
        r0_abs = froguard(slot_sum(slots, 6, sys));
        r_abs = r0_abs;
        if (ts == 0) g_rabs[sys] = r_abs;
      } else {
        const float s_abs = froguard(slot_sum(slots, 6, sys));
        if (s_abs <= THRC) {
          // C3: x += alpha*p ; r = s  (terminal for this system)
#pragma unroll
          for (int k = 0; k < EPT; k++) {
            const int idx = ts + k * TPS;
            xs[idx] = xs[idx] + alpha * preg[k];
            rreg[k] = rreg[k] - alpha * vreg[k];
          }
          r_abs = s_abs;
          if (ts == 0) g_rabs[sys] = r_abs;
        } else {
          C4 = true;
          double ptt = 0, pts = 0;
#pragma unroll
          for (int k = 0; k < EPT; k++) {
            const int idx = ts + k * TPS;
            const int i = (int)((unsigned)idx / (unsigned)NXI);
            const int j = idx - i * NXI;
            const float sc = rreg[k] - alpha * vreg[k];
            const float tv = applyA(ss, sc, idx, i, j, boos, bmos, boms, bops, bpos);
            treg[k] = tv;
            ptt += (double)tv * (double)tv;
            pts += (double)tv * (double)sc;
          }
          bred_store(ptt, pts, 0.0, slots, 9, sys, bs, tid);
        }
      }
    }
    if (ts == 0) g_c4[sys] = C4 ? 1 : 0;  // unconditional publish every iteration
    grid_bar(bar, &bphase);  // S3

    bool anyC4 = false;
#pragma unroll
    for (int s2 = 0; s2 < NSYS; s2++) anyC4 = anyC4 || (vc4[s2] != 0);
    if (anyC4) {
      // ---- Phase 4: omega; x += alpha*p + omega*s ; r = s - omega*t ; reduce <r,r>, <r,r0>
      if (C4) {
        const float tt  = (float)slot_sum(slots, 9, sys);
        const float tsv = (float)slot_sum(slots, 10, sys);
        omega = tsv / tt;
        double prr = 0, prh = 0;
#pragma unroll
        for (int k = 0; k < EPT; k++) {
          const int idx = ts + k * TPS;
          const float sc = rreg[k] - alpha * vreg[k];
          xs[idx] = xs[idx] + alpha * preg[k] + omega * sc;
          const float rn = sc - omega * treg[k];
          rreg[k] = rn;
          prr += (double)rn * (double)rn;
          prh += (double)rn * (double)r0reg[k];
        }
        bred_store(prr, prh, 0.0, slots, 12, sys, bs, tid);
      }
      grid_bar(bar, &bphase);  // S4
      // ---- Phase 5: beta; p = r + beta*(p - omega*v)
      if (C4) {
        const float rr_abs = froguard(slot_sum(slots, 12, sys));
        const float rho_new = (float)slot_sum(slots, 13, sys);
        const float beta = (alpha / omega) * (rho_new / rho);  // den == old rho
#pragma unroll
        for (int k = 0; k < EPT; k++) {
          const int idx = ts + k * TPS;
          const float pn = rreg[k] + beta * (preg[k] - omega * vreg[k]);
          preg[k] = pn;
          ps[idx] = pn;
        }
        r_abs = rr_abs;
        if (ts == 0) g_rabs[sys] = r_abs;
      }
      grid_bar(bar, &bphase);  // S5
    }
  }
  // x already lives in d_out; nothing else to do.
}

extern "C" void kernel_launch(void* const* d_in, const int* in_sizes, int n_in,
                              void* d_out, int out_size, void* d_ws, size_t ws_size,
                              hipStream_t stream) {
  const float* V  = (const float*)d_in[0];
  const float* M1 = (const float*)d_in[1];
  const float* M2 = (const float*)d_in[2];
  float* xout = (float*)d_out;
  float* wsf  = (float*)d_ws;
  // zero the grid-barrier counter line (ws is re-poisoned to 0xAA before each call)
  hipMemsetAsync(d_ws, 0, 128, stream);
  bicg_kernel<<<dim3(NBLK), dim3(NTHR), 0, stream>>>(V, M1, M2, xout, wsf);
}

// Round 3
// 2556.253 us; speedup vs baseline: 2.3337x; 2.3337x over previous
//
#include <hip/hip_runtime.h>

#define NXI 384
#define NG  (NXI*NXI)          // 147456 elements per system
#define NSYS 8
#define BPS 32                 // blocks per system
#define NBLK (NSYS*BPS)        // 256 blocks
#define NTHR 256
#define TPS (BPS*NTHR)         // 8192 threads per system
#define EPT (NG/TPS)           // 18 elements per thread

// thr = EPS*NX*NY = 1e-9*147456
#define THRC 1.47456e-4f

// ---- relaxed agent-scope (fabric-coherent, no cache flush) accessors ----
__device__ __forceinline__ float aloadf(const float* p) {
  return __hip_atomic_load(p, __ATOMIC_RELAXED, __HIP_MEMORY_SCOPE_AGENT);
}
__device__ __forceinline__ void astoref(float* p, float v) {
  __hip_atomic_store(p, v, __ATOMIC_RELAXED, __HIP_MEMORY_SCOPE_AGENT);
}
__device__ __forceinline__ double aloadd(const double* p) {
  return __hip_atomic_load(p, __ATOMIC_RELAXED, __HIP_MEMORY_SCOPE_AGENT);
}
__device__ __forceinline__ void astored(double* p, double v) {
  __hip_atomic_store(p, v, __ATOMIC_RELAXED, __HIP_MEMORY_SCOPE_AGENT);
}

__device__ __forceinline__ double wave_red(double v) {
#pragma unroll
  for (int off = 32; off > 0; off >>= 1) v += __shfl_down(v, off, 64);
  return v;
}

// ---- per-system barrier: 32 blocks, one counter line, NO scoped fences ----
// Stores preceding the barrier are relaxed-agent atomics (already fabric-
// visible once vmcnt drains); each wave drains its own vmcnt before s_barrier,
// so the leader's arrival atomic strictly follows all of the block's stores.
__device__ __forceinline__ void sys_bar(unsigned* sbar, unsigned* phase, int tid) {
  __atomic_signal_fence(__ATOMIC_SEQ_CST);
  __builtin_amdgcn_s_waitcnt(0);   // drain this wave's outstanding memory ops
  __syncthreads();
  if (tid == 0) {
    const unsigned ph = ++(*phase);
    __hip_atomic_fetch_add(sbar, 1u, __ATOMIC_RELAXED, __HIP_MEMORY_SCOPE_AGENT);
    while (__hip_atomic_load(sbar, __ATOMIC_RELAXED, __HIP_MEMORY_SCOPE_AGENT) < ph * BPS) {
      __builtin_amdgcn_s_sleep(2);
    }
  } else {
    ++(*phase);
  }
  __syncthreads();
  __atomic_signal_fence(__ATOMIC_SEQ_CST);
}

// Block-reduce 3 doubles and agent-store to slot channels [chan0..chan0+2][sys][bs].
__device__ __forceinline__ void bred3(double v0, double v1, double v2,
                                      double* slots, int chan0,
                                      int sys, int bs, int tid) {
  __shared__ double sred[4][3];
  const int wid = tid >> 6, lane = tid & 63;
  const double w0 = wave_red(v0);
  const double w1 = wave_red(v1);
  const double w2 = wave_red(v2);
  if (lane == 0) { sred[wid][0] = w0; sred[wid][1] = w1; sred[wid][2] = w2; }
  __syncthreads();
  if (tid == 0) {
#pragma unroll
    for (int q = 0; q < 3; q++) {
      const double a = sred[0][q] + sred[1][q] + sred[2][q] + sred[3][q];
      astored(slots + (size_t)(chan0 + q) * NBLK + sys * BPS + bs, a);
    }
  }
  __syncthreads();
}

// Deterministic butterfly sum of one channel's 32 per-block partials.
// Every lane loads partial (lane&31); xor-butterfly over 5 levels gives the
// identical bit-exact sum in every lane of every block of the system.
__device__ __forceinline__ double shred(const double* slots, int chan, int sys, int lane) {
  double v = aloadd(slots + (size_t)chan * NBLK + sys * BPS + (lane & 31));
  v += __shfl_xor(v, 1, 64);
  v += __shfl_xor(v, 2, 64);
  v += __shfl_xor(v, 4, 64);
  v += __shfl_xor(v, 8, 64);
  v += __shfl_xor(v, 16, 64);
  return v;
}

// fro() guard semantics from the reference: sqrt(sq) if sq>0 else 0
__device__ __forceinline__ float froguard(double sq) {
  return sq > 0.0 ? (float)sqrt(sq) : 0.0f;
}

// 5-point stencil apply, symmetric (edge-clamp) boundary. uc = center value.
// Neighbors cross block ownership -> agent loads. Coeffs are own-thread -> plain.
__device__ __forceinline__ float applyA(const float* u, float uc, int idx, int i, int j,
                                        const float* cboo, const float* cbmo,
                                        const float* cbom, const float* cbop,
                                        const float* cbpo) {
  const float um = (i == 0)       ? uc : aloadf(u + idx - NXI);
  const float ud = (i == NXI - 1) ? uc : aloadf(u + idx + NXI);
  const float ul = (j == 0)       ? uc : aloadf(u + idx - 1);
  const float ur = (j == NXI - 1) ? uc : aloadf(u + idx + 1);
  return cboo[idx] * uc + cbmo[idx] * um + cbom[idx] * ul + cbop[idx] * ur + cbpo[idx] * ud;
}

__global__ __launch_bounds__(NTHR, 1) void bicg_kernel(
    const float* __restrict__ V, const float* __restrict__ M1, const float* __restrict__ M2,
    float* __restrict__ xout, float* __restrict__ wsf) {
  const int blk = blockIdx.x;
  const int sys = blk & (NSYS - 1);   // blk%8 -> system; also pins system to one XCD (perf only)
  const int bs  = blk >> 3;
  const int tid = threadIdx.x;
  const int ts  = bs * NTHR + tid;    // thread-in-system [0,8192)
  const int lane = tid & 63;

  // ---- workspace layout ----
  unsigned* bar  = (unsigned*)wsf + sys * 32;        // per-system counter line (128B apart), memset 0
  double* slots  = (double*)(wsf + 1024);            // byte offset 4096; 24 chans * 256 doubles
  float* base    = wsf + 16384;                      // byte offset 64KB
  float* cboo = base + 0ull * NSYS * NG;
  float* cbmo = base + 1ull * NSYS * NG;
  float* cbom = base + 2ull * NSYS * NG;
  float* cbop = base + 3ull * NSYS * NG;
  float* cbpo = base + 4ull * NSYS * NG;
  float* pva  = base + 5ull * NSYS * NG;
  float* sva  = base + 6ull * NSYS * NG;

  unsigned bphase = 0;

  const size_t so = (size_t)sys * NG;
  const float* Vb  = V  + so;
  const float* M1b = M1 + so;
  const float* M2b = M2 + so;
  float* boos = cboo + so; float* bmos = cbmo + so; float* boms = cbom + so;
  float* bops = cbop + so; float* bpos = cbpo + so;
  float* xs = xout + so;   // x lives directly in d_out (interior layout matches output)
  float* ps = pva + so;
  float* ss = sva + so;

  // ---------- Phase 0: stencil coefficients + V-mean partial ----------
  double vsum = 0.0;
#pragma unroll
  for (int k = 0; k < EPT; k++) {
    const int idx = ts + k * TPS;
    vsum += (double)Vb[idx];
    const int i = (int)((unsigned)idx / (unsigned)NXI);
    const int j = idx - i * NXI;
    const int a0 = (i - 1 < 0) ? 0 : i - 1;
    const int a1 = i;
    const int a2 = (i + 1 > NXI - 1) ? NXI - 1 : i + 1;
    const int b0 = (j - 1 < 0) ? 0 : j - 1;
    const int b1 = j;
    const int b2 = (j + 1 > NXI - 1) ? NXI - 1 : j + 1;
    const float vc = Vb[b1 * NXI + a1] + 1.0f;
    const float vu = Vb[b1 * NXI + a0] + 1.0f;
    const float vd = Vb[b1 * NXI + a2] + 1.0f;
    const float vl = Vb[b0 * NXI + a1] + 1.0f;
    const float vr = Vb[b2 * NXI + a1] + 1.0f;
    const float D1A = M1b[b1 * NXI + a1] * ((vd - vc) / (0.5f * (vd + vc)));
    const float D1B = M1b[b1 * NXI + a0] * ((vc - vu) / (0.5f * (vc + vu)));
    const float D2A = M2b[b1 * NXI + a1] * ((vr - vc) / (0.5f * (vr + vc)));
    const float D2B = M2b[b0 * NXI + a1] * ((vc - vl) / (0.5f * (vc + vl)));
    boos[idx] = 41.0f - 5.0f * (D1B - D1A) - 5.0f * (D2B - D2A);
    bpos[idx] = -10.0f + 5.0f * D1A;
    bmos[idx] = -10.0f - 5.0f * D1B;
    bops[idx] = -10.0f + 5.0f * D2A;
    boms[idx] = -10.0f - 5.0f * D2B;
  }
  bred3(vsum, 0.0, 0.0, slots, 0, sys, bs, tid);
  sys_bar(bar, &bphase, tid);  // S0a

  // ---------- Phase 0b: x=mb; p=r=r0=b-Ax (x const -> rowsum trick) ----------
  const float mb = (float)(shred(slots, 0, sys, lane) / (double)NG) + 1.0f;  // mean(V)+OFFSET
  float preg[EPT], rreg[EPT], r0reg[EPT], vreg[EPT], treg[EPT];
  double r0sq = 0.0;
#pragma unroll
  for (int k = 0; k < EPT; k++) {
    const int idx = ts + k * TPS;
    const float ax = boos[idx] * mb + bmos[idx] * mb + boms[idx] * mb + bops[idx] * mb + bpos[idx] * mb;
    const float pn = mb - ax;
    astoref(xs + idx, mb);
    astoref(ps + idx, pn);
    preg[k] = pn; rreg[k] = pn; r0reg[k] = pn;
    r0sq += (double)pn * (double)pn;
  }
  bred3(r0sq, 0.0, 0.0, slots, 3, sys, bs, tid);
  sys_bar(bar, &bphase, tid);  // S0b
  float r0_abs = froguard(shred(slots, 3, sys, lane));
  float r_abs = r0_abs;

  float alpha = 0.f, omega = 0.f, rho = 0.f;

  for (int it = 0; it < 30; ++it) {
    if (!(r_abs > THRC)) break;  // uniform within system (identical shred in all blocks)

    // ---- Phase 1: v = A p ; reduce sigma=<v,r0>, vabs2=<v,v>, rho=<r,r0>
    {
      double psig = 0, pvab = 0, prho = 0;
#pragma unroll
      for (int k = 0; k < EPT; k++) {
        const int idx = ts + k * TPS;
        const int i = (int)((unsigned)idx / (unsigned)NXI);
        const int j = idx - i * NXI;
        const float vv = applyA(ps, preg[k], idx, i, j, boos, bmos, boms, bops, bpos);
        vreg[k] = vv;
        psig += (double)vv * (double)r0reg[k];
        pvab += (double)vv * (double)vv;
        prho += (double)rreg[k] * (double)r0reg[k];
      }
      bred3(psig, pvab, prho, slots, 6, sys, bs, tid);
    }
    sys_bar(bar, &bphase, tid);  // S1

    const float sigma = (float)shred(slots, 6, sys, lane);
    const float v_abs = froguard(shred(slots, 7, sys, lane));
    rho = (float)shred(slots, 8, sys, lane);
    const bool RES = (sigma <= 1e-9f * v_abs * r0_abs);  // uniform

    if (RES) {
      // restart: p = r = r0 = b - A x ; reduce <p,p>
      double pacc = 0;
#pragma unroll
      for (int k = 0; k < EPT; k++) {
        const int idx = ts + k * TPS;
        const int i = (int)((unsigned)idx / (unsigned)NXI);
        const int j = idx - i * NXI;
        const float xc = aloadf(xs + idx);
        const float ax = applyA(xs, xc, idx, i, j, boos, bmos, boms, bops, bpos);
        const float pn = mb - ax;
        astoref(ps + idx, pn);
        preg[k] = pn; rreg[k] = pn; r0reg[k] = pn;
        pacc += (double)pn * (double)pn;
      }
      bred3(pacc, 0.0, 0.0, slots, 9, sys, bs, tid);
      sys_bar(bar, &bphase, tid);  // S2 (restart flavor)
      r0_abs = froguard(shred(slots, 9, sys, lane));
      r_abs = r0_abs;
      continue;
    }

    // ---- Phase 2: s = r - alpha*v ; reduce <s,s>
    alpha = rho / sigma;
    {
      double pacc = 0;
#pragma unroll
      for (int k = 0; k < EPT; k++) {
        const int idx = ts + k * TPS;
        const float sv = rreg[k] - alpha * vreg[k];
        astoref(ss + idx, sv);
        pacc += (double)sv * (double)sv;
      }
      bred3(pacc, 0.0, 0.0, slots, 9, sys, bs, tid);
    }
    sys_bar(bar, &bphase, tid);  // S2

    const float s_abs = froguard(shred(slots, 9, sys, lane));
    if (s_abs <= THRC) {
      // C3: x += alpha*p ; r = s (terminal: r_abs = s_abs <= thr -> break at top)
#pragma unroll
      for (int k = 0; k < EPT; k++) {
        const int idx = ts + k * TPS;
        astoref(xs + idx, aloadf(xs + idx) + alpha * preg[k]);
        rreg[k] = rreg[k] - alpha * vreg[k];
      }
      r_abs = s_abs;
      continue;
    }

    // ---- Phase 3: t = A s ; reduce <t,t>, <t,s>
    {
      double ptt = 0, pts = 0;
#pragma unroll
      for (int k = 0; k < EPT; k++) {
        const int idx = ts + k * TPS;
        const int i = (int)((unsigned)idx / (unsigned)NXI);
        const int j = idx - i * NXI;
        const float sc = rreg[k] - alpha * vreg[k];
        const float tv = applyA(ss, sc, idx, i, j, boos, bmos, boms, bops, bpos);
        treg[k] = tv;
        ptt += (double)tv * (double)tv;
        pts += (double)tv * (double)sc;
      }
      bred3(ptt, pts, 0.0, slots, 12, sys, bs, tid);
    }
    sys_bar(bar, &bphase, tid);  // S3

    // ---- Phase 4: omega; x += alpha*p + omega*s ; r = s - omega*t ; <r,r>, <r,r0>
    {
      const float tt  = (float)shred(slots, 12, sys, lane);
      const float tsv = (float)shred(slots, 13, sys, lane);
      omega = tsv / tt;
      double prr = 0, prh = 0;
#pragma unroll
      for (int k = 0; k < EPT; k++) {
        const int idx = ts + k * TPS;
        const float sc = rreg[k] - alpha * vreg[k];
        astoref(xs + idx, aloadf(xs + idx) + alpha * preg[k] + omega * sc);
        const float rn = sc - omega * treg[k];
        rreg[k] = rn;
        prr += (double)rn * (double)rn;
        prh += (double)rn * (double)r0reg[k];
      }
      bred3(prr, prh, 0.0, slots, 15, sys, bs, tid);
    }
    sys_bar(bar, &bphase, tid);  // S4

    // ---- Phase 5: beta; p = r + beta*(p - omega*v)
    {
      const float rr_abs  = froguard(shred(slots, 15, sys, lane));
      const float rho_new = (float)shred(slots, 16, sys, lane);
      const float beta = (alpha / omega) * (rho_new / rho);  // den == old rho
#pragma unroll
      for (int k = 0; k < EPT; k++) {
        const int idx = ts + k * TPS;
        const float pn = rreg[k] + beta * (preg[k] - omega * vreg[k]);
        preg[k] = pn;
        astoref(ps + idx, pn);
      }
      r_abs = rr_abs;
    }
    sys_bar(bar, &bphase, tid);  // S5 (publish p before next matvec)
  }
  // x already lives in d_out (agent stores); kernel-end release makes it host-visible.
}

extern "C" void kernel_launch(void* const* d_in, const int* in_sizes, int n_in,
                              void* d_out, int out_size, void* d_ws, size_t ws_size,
                              hipStream_t stream) {
  const float* V  = (const float*)d_in[0];
  const float* M1 = (const float*)d_in[1];
  const float* M2 = (const float*)d_in[2];
  float* xout = (float*)d_out;
  float* wsf  = (float*)d_ws;
  // zero the 8 per-system barrier counter lines (ws is re-poisoned each call)
  hipMemsetAsync(d_ws, 0, 4096, stream);
  bicg_kernel<<<dim3(NBLK), dim3(NTHR), 0, stream>>>(V, M1, M2, xout, wsf);
}

// Round 4
// 1493.212 us; speedup vs baseline: 3.9951x; 1.7119x over previous
//
#include <hip/hip_runtime.h>

#define NXI 384
#define NG  (NXI*NXI)          // 147456 elements per system
#define NSYS 8
#define BPS 32                 // blocks per system
#define NBLK (NSYS*BPS)        // 256 blocks
#define NTHR 256
#define ROWS_PB 12             // rows per block (384/32)
#define EPB (ROWS_PB*NXI)      // 4608 elements per block
#define EPT (EPB/NTHR)         // 18 elements per thread

// thr = EPS*NX*NY = 1e-9*147456
#define THRC 1.47456e-4f

// ---- relaxed agent-scope (fabric-coherent, cache-bypassing) accessors ----
__device__ __forceinline__ float aloadf(const float* p) {
  return __hip_atomic_load(p, __ATOMIC_RELAXED, __HIP_MEMORY_SCOPE_AGENT);
}
__device__ __forceinline__ void astoref(float* p, float v) {
  __hip_atomic_store(p, v, __ATOMIC_RELAXED, __HIP_MEMORY_SCOPE_AGENT);
}
__device__ __forceinline__ double aloadd(const double* p) {
  return __hip_atomic_load(p, __ATOMIC_RELAXED, __HIP_MEMORY_SCOPE_AGENT);
}
__device__ __forceinline__ void astored(double* p, double v) {
  __hip_atomic_store(p, v, __ATOMIC_RELAXED, __HIP_MEMORY_SCOPE_AGENT);
}

__device__ __forceinline__ double wave_red(double v) {
#pragma unroll
  for (int off = 32; off > 0; off >>= 1) v += __shfl_down(v, off, 64);
  return v;
}

// ---- per-system barrier: 32 blocks, one counter line, no scoped fences ----
// Every wave drains its own memory ops (s_waitcnt 0) before the block syncs,
// so the leader's arrival atomic strictly follows all of the block's agent
// stores (same construction validated in rounds 2-3).
__device__ __forceinline__ void sys_bar(unsigned* sbar, unsigned* phase, int tid) {
  __atomic_signal_fence(__ATOMIC_SEQ_CST);
  __builtin_amdgcn_s_waitcnt(0);
  __syncthreads();
  if (tid == 0) {
    const unsigned ph = ++(*phase);
    __hip_atomic_fetch_add(sbar, 1u, __ATOMIC_RELAXED, __HIP_MEMORY_SCOPE_AGENT);
    while (__hip_atomic_load(sbar, __ATOMIC_RELAXED, __HIP_MEMORY_SCOPE_AGENT) < ph * BPS) {
      __builtin_amdgcn_s_sleep(1);
    }
  } else {
    ++(*phase);
  }
  __syncthreads();
  __atomic_signal_fence(__ATOMIC_SEQ_CST);
}

// Block-reduce 3 doubles and agent-store to slot channels [chan0..chan0+2][sys][bs].
__device__ __forceinline__ void bred3(double v0, double v1, double v2,
                                      double* slots, int chan0,
                                      int sys, int bs, int tid) {
  __shared__ double sred[4][3];
  const int wid = tid >> 6, lane = tid & 63;
  const double w0 = wave_red(v0);
  const double w1 = wave_red(v1);
  const double w2 = wave_red(v2);
  if (lane == 0) { sred[wid][0] = w0; sred[wid][1] = w1; sred[wid][2] = w2; }
  __syncthreads();
  if (tid == 0) {
#pragma unroll
    for (int q = 0; q < 3; q++) {
      const double a = sred[0][q] + sred[1][q] + sred[2][q] + sred[3][q];
      astored(slots + (size_t)(chan0 + q) * NBLK + sys * BPS + bs, a);
    }
  }
  __syncthreads();
}

// Deterministic butterfly sum of one channel's 32 per-block partials; identical
// bit-exact result in every lane of every block of the system.
__device__ __forceinline__ double shred(const double* slots, int chan, int sys, int lane) {
  double v = aloadd(slots + (size_t)chan * NBLK + sys * BPS + (lane & 31));
  v += __shfl_xor(v, 1, 64);
  v += __shfl_xor(v, 2, 64);
  v += __shfl_xor(v, 4, 64);
  v += __shfl_xor(v, 8, 64);
  v += __shfl_xor(v, 16, 64);
  return v;
}

__device__ __forceinline__ float froguard(double sq) {
  return sq > 0.0 ? (float)sqrt(sq) : 0.0f;
}

// Publish one owned element into the LDS slab (+ global halo row if boundary).
__device__ __forceinline__ void publish(float val, int e, float* lds, float* hal) {
  const int lr = e / NXI, c = e - lr * NXI;
  lds[(lr + 1) * NXI + c] = val;
  if (e < NXI)             astoref(hal + c, val);              // own top row
  if (e >= EPB - NXI)      astoref(hal + NXI + c, val);        // own bottom row
}

// Pull neighbor blocks' boundary rows into LDS halo rows 0 and 13.
__device__ __forceinline__ void load_halo(float* lds, const float* ghalo_sys, int bs, int tid) {
  for (int c = tid; c < NXI; c += NTHR) {
    if (bs > 0)       lds[c] = aloadf(ghalo_sys + (size_t)(bs - 1) * 2 * NXI + NXI + c);
    if (bs < BPS - 1) lds[(ROWS_PB + 1) * NXI + c] = aloadf(ghalo_sys + (size_t)(bs + 1) * 2 * NXI + c);
  }
  __syncthreads();
}

// 5-point stencil from the LDS slab; uc = center (register). Symmetric clamp.
__device__ __forceinline__ float applyA_lds(const float* lds, float uc, int e, int gr0,
                                            const float* boo, const float* bmo,
                                            const float* bom, const float* bop,
                                            const float* bpo) {
  const int lr = e / NXI, c = e - lr * NXI;
  const int gr = gr0 + lr;
  const float um = (gr == 0)       ? uc : lds[lr * NXI + c];
  const float ud = (gr == NXI - 1) ? uc : lds[(lr + 2) * NXI + c];
  const float ul = (c == 0)        ? uc : lds[(lr + 1) * NXI + c - 1];
  const float ur = (c == NXI - 1)  ? uc : lds[(lr + 1) * NXI + c + 1];
  return boo[e] * uc + bmo[e] * um + bom[e] * ul + bop[e] * ur + bpo[e] * ud;
}

__global__ __launch_bounds__(NTHR, 1) void bicg_kernel(
    const float* __restrict__ V, const float* __restrict__ M1, const float* __restrict__ M2,
    float* __restrict__ xout, float* __restrict__ wsf) {
  const int blk = blockIdx.x;
  const int sys = blk & (NSYS - 1);   // blk%8: system == XCD-swizzle slot (perf only)
  const int bs  = blk >> 3;           // slab index within system
  const int tid = threadIdx.x;
  const int lane = tid & 63;
  const int gr0 = bs * ROWS_PB;       // first global row of this block's slab

  __shared__ float lds[(ROWS_PB + 2) * NXI];   // 14x384 slab incl. halo rows

  // ---- workspace layout ----
  unsigned* bar  = (unsigned*)wsf + sys * 32;          // per-system counter line (memset 0)
  double* slots  = (double*)(wsf + 1024);              // 24 chans * 256 doubles (49KB)
  float* ghalo   = wsf + 16384;                        // [sys][bs][2][384] p/s halos (786KB)
  float* ghalo2  = ghalo + (size_t)NSYS * BPS * 2 * NXI; // x halos for restart (786KB)
  float* base    = ghalo2 + (size_t)NSYS * BPS * 2 * NXI;
  float* cboo = base + 0ull * NSYS * NG;
  float* cbmo = base + 1ull * NSYS * NG;
  float* cbom = base + 2ull * NSYS * NG;
  float* cbop = base + 3ull * NSYS * NG;
  float* cbpo = base + 4ull * NSYS * NG;

  unsigned bphase = 0;

  const size_t so = (size_t)sys * NG;
  const size_t bo = so + (size_t)bs * EPB;            // this block's slab base in system arrays
  const float* Vb  = V  + so;
  const float* M1b = M1 + so;
  const float* M2b = M2 + so;
  // per-block coefficient slabs (same-thread write/read -> plain cached)
  float* boos = cboo + bo; float* bmos = cbmo + bo; float* boms = cbom + bo;
  float* bops = cbop + bo; float* bpos = cbpo + bo;
  float* xs = xout + bo;                               // final write-out only
  float* ghalo_sys = ghalo  + (size_t)sys * BPS * 2 * NXI;
  float* ghalo2_sys= ghalo2 + (size_t)sys * BPS * 2 * NXI;
  float* hal  = ghalo_sys  + (size_t)bs * 2 * NXI;     // own p/s halo rows
  float* hal2 = ghalo2_sys + (size_t)bs * 2 * NXI;     // own x halo rows

  // ---------- Phase 0: stencil coefficients + V-mean partial ----------
  double vsum = 0.0;
#pragma unroll
  for (int k = 0; k < EPT; k++) {
    const int e = tid + k * NTHR;
    const int idx = bs * EPB + e;                      // index within system
    vsum += (double)Vb[idx];
    const int i = (int)((unsigned)idx / (unsigned)NXI);
    const int j = idx - i * NXI;
    const int a0 = (i - 1 < 0) ? 0 : i - 1;
    const int a1 = i;
    const int a2 = (i + 1 > NXI - 1) ? NXI - 1 : i + 1;
    const int b0 = (j - 1 < 0) ? 0 : j - 1;
    const int b1 = j;
    const int b2 = (j + 1 > NXI - 1) ? NXI - 1 : j + 1;
    const float vc = Vb[b1 * NXI + a1] + 1.0f;
    const float vu = Vb[b1 * NXI + a0] + 1.0f;
    const float vd = Vb[b1 * NXI + a2] + 1.0f;
    const float vl = Vb[b0 * NXI + a1] + 1.0f;
    const float vr = Vb[b2 * NXI + a1] + 1.0f;
    const float D1A = M1b[b1 * NXI + a1] * ((vd - vc) / (0.5f * (vd + vc)));
    const float D1B = M1b[b1 * NXI + a0] * ((vc - vu) / (0.5f * (vc + vu)));
    const float D2A = M2b[b1 * NXI + a1] * ((vr - vc) / (0.5f * (vr + vc)));
    const float D2B = M2b[b0 * NXI + a1] * ((vc - vl) / (0.5f * (vc + vl)));
    boos[e] = 41.0f - 5.0f * (D1B - D1A) - 5.0f * (D2B - D2A);
    bpos[e] = -10.0f + 5.0f * D1A;
    bmos[e] = -10.0f - 5.0f * D1B;
    bops[e] = -10.0f + 5.0f * D2A;
    boms[e] = -10.0f - 5.0f * D2B;
  }
  bred3(vsum, 0.0, 0.0, slots, 0, sys, bs, tid);
  sys_bar(bar, &bphase, tid);  // S0a

  // ---------- Phase 0b: x=mb; p=r=r0=b-Ax (x const -> rowsum trick) ----------
  const float mb = (float)(shred(slots, 0, sys, lane) / (double)NG) + 1.0f;  // mean(V)+OFFSET
  float preg[EPT], rreg[EPT], r0reg[EPT], vreg[EPT], treg[EPT], xreg[EPT];
  double r0sq = 0.0;
#pragma unroll
  for (int k = 0; k < EPT; k++) {
    const int e = tid + k * NTHR;
    const float ax = (boos[e] + bmos[e] + boms[e] + bops[e] + bpos[e]) * mb;
    const float pn = mb - ax;
    xreg[k] = mb;
    publish(pn, e, lds, hal);
    preg[k] = pn; rreg[k] = pn; r0reg[k] = pn;
    r0sq += (double)pn * (double)pn;
  }
  bred3(r0sq, 0.0, 0.0, slots, 3, sys, bs, tid);
  sys_bar(bar, &bphase, tid);  // S0b (publishes p halos + r0sq)
  float r0_abs = froguard(shred(slots, 3, sys, lane));
  float r_abs = r0_abs;

  float alpha = 0.f, omega = 0.f, rho = 0.f;

  for (int it = 0; it < 30; ++it) {
    if (!(r_abs > THRC)) break;  // uniform within system

    // ---- Phase 1: v = A p ; reduce sigma=<v,r0>, vabs2=<v,v>, rho=<r,r0>
    load_halo(lds, ghalo_sys, bs, tid);   // p halos (published before last barrier)
    {
      double psig = 0, pvab = 0, prho = 0;
#pragma unroll
      for (int k = 0; k < EPT; k++) {
        const int e = tid + k * NTHR;
        const float vv = applyA_lds(lds, preg[k], e, gr0, boos, bmos, boms, bops, bpos);
        vreg[k] = vv;
        psig += (double)vv * (double)r0reg[k];
        pvab += (double)vv * (double)vv;
        prho += (double)rreg[k] * (double)r0reg[k];
      }
      bred3(psig, pvab, prho, slots, 6, sys, bs, tid);
    }
    sys_bar(bar, &bphase, tid);  // S1

    const float sigma = (float)shred(slots, 6, sys, lane);
    const float v_abs = froguard(shred(slots, 7, sys, lane));
    rho = (float)shred(slots, 8, sys, lane);
    const bool RES = (sigma <= 1e-9f * v_abs * r0_abs);  // uniform

    if (RES) {
      // restart: p = r = r0 = b - A x ; reduce <p,p>
      __syncthreads();  // phase-1 slab reads done before overwrite
#pragma unroll
      for (int k = 0; k < EPT; k++) {
        const int e = tid + k * NTHR;
        publish(xreg[k], e, lds, hal2);   // x -> slab + x-halo buffer
      }
      sys_bar(bar, &bphase, tid);  // SR1 (publish x halos)
      load_halo(lds, ghalo2_sys, bs, tid);
      float pnl[EPT];
#pragma unroll
      for (int k = 0; k < EPT; k++) {
        const int e = tid + k * NTHR;
        const float ax = applyA_lds(lds, xreg[k], e, gr0, boos, bmos, boms, bops, bpos);
        pnl[k] = mb - ax;
      }
      __syncthreads();  // all slab reads done before overwrite with p
      double pacc = 0;
#pragma unroll
      for (int k = 0; k < EPT; k++) {
        const int e = tid + k * NTHR;
        const float pn = pnl[k];
        publish(pn, e, lds, hal);
        preg[k] = pn; rreg[k] = pn; r0reg[k] = pn;
        pacc += (double)pn * (double)pn;
      }
      bred3(pacc, 0.0, 0.0, slots, 9, sys, bs, tid);
      sys_bar(bar, &bphase, tid);  // SR2 (publish p halos + <p,p>)
      r0_abs = froguard(shred(slots, 9, sys, lane));
      r_abs = r0_abs;
      continue;
    }

    // ---- Phase 2: s = r - alpha*v ; reduce <s,s>  (s -> slab + halos)
    alpha = rho / sigma;
    __syncthreads();  // phase-1 slab reads done before overwrite
    {
      double pacc = 0;
#pragma unroll
      for (int k = 0; k < EPT; k++) {
        const int e = tid + k * NTHR;
        const float sv = rreg[k] - alpha * vreg[k];
        publish(sv, e, lds, hal);
        pacc += (double)sv * (double)sv;
      }
      bred3(pacc, 0.0, 0.0, slots, 9, sys, bs, tid);
    }
    sys_bar(bar, &bphase, tid);  // S2

    const float s_abs = froguard(shred(slots, 9, sys, lane));
    if (s_abs <= THRC) {
      // C3: x += alpha*p ; r = s (terminal: loop breaks at top)
#pragma unroll
      for (int k = 0; k < EPT; k++) {
        xreg[k] = xreg[k] + alpha * preg[k];
        rreg[k] = rreg[k] - alpha * vreg[k];
      }
      r_abs = s_abs;
      continue;
    }

    // ---- Phase 3: t = A s ; reduce <t,t>, <t,s>
    load_halo(lds, ghalo_sys, bs, tid);   // s halos
    {
      double ptt = 0, pts = 0;
#pragma unroll
      for (int k = 0; k < EPT; k++) {
        const int e = tid + k * NTHR;
        const float sc = rreg[k] - alpha * vreg[k];
        const float tv = applyA_lds(lds, sc, e, gr0, boos, bmos, boms, bops, bpos);
        treg[k] = tv;
        ptt += (double)tv * (double)tv;
        pts += (double)tv * (double)sc;
      }
      bred3(ptt, pts, 0.0, slots, 12, sys, bs, tid);
    }
    sys_bar(bar, &bphase, tid);  // S3

    // ---- Phase 4: omega; x += alpha*p + omega*s ; r = s - omega*t ; <r,r>, <r,r0>
    {
      const float tt  = (float)shred(slots, 12, sys, lane);
      const float tsv = (float)shred(slots, 13, sys, lane);
      omega = tsv / tt;
      double prr = 0, prh = 0;
#pragma unroll
      for (int k = 0; k < EPT; k++) {
        const float sc = rreg[k] - alpha * vreg[k];
        xreg[k] = xreg[k] + alpha * preg[k] + omega * sc;
        const float rn = sc - omega * treg[k];
        rreg[k] = rn;
        prr += (double)rn * (double)rn;
        prh += (double)rn * (double)r0reg[k];
      }
      bred3(prr, prh, 0.0, slots, 15, sys, bs, tid);
    }
    sys_bar(bar, &bphase, tid);  // S4

    // ---- Phase 5: beta; p = r + beta*(p - omega*v)  (p -> slab + halos)
    __syncthreads();  // phase-3 slab reads long done (S3/S4 passed); cheap safety
    {
      const float rr_abs  = froguard(shred(slots, 15, sys, lane));
      const float rho_new = (float)shred(slots, 16, sys, lane);
      const float beta = (alpha / omega) * (rho_new / rho);  // den == old rho
#pragma unroll
      for (int k = 0; k < EPT; k++) {
        const int e = tid + k * NTHR;
        const float pn = rreg[k] + beta * (preg[k] - omega * vreg[k]);
        preg[k] = pn;
        publish(pn, e, lds, hal);
      }
      r_abs = rr_abs;
    }
    sys_bar(bar, &bphase, tid);  // S5 (publish p halos before next matvec)
  }

  // final write-out of x (plain stores; end-of-kernel release makes host-visible)
#pragma unroll
  for (int k = 0; k < EPT; k++) {
    const int e = tid + k * NTHR;
    xs[e] = xreg[k];
  }
}

extern "C" void kernel_launch(void* const* d_in, const int* in_sizes, int n_in,
                              void* d_out, int out_size, void* d_ws, size_t ws_size,
                              hipStream_t stream) {
  const float* V  = (const float*)d_in[0];
  const float* M1 = (const float*)d_in[1];
  const float* M2 = (const float*)d_in[2];
  float* xout = (float*)d_out;
  float* wsf  = (float*)d_ws;
  // zero the 8 per-system barrier counter lines (ws is re-poisoned each call)
  hipMemsetAsync(d_ws, 0, 4096, stream);
  bicg_kernel<<<dim3(NBLK), dim3(NTHR), 0, stream>>>(V, M1, M2, xout, wsf);
}

// Round 5
// 732.809 us; speedup vs baseline: 8.1407x; 2.0377x over previous
//
#include <hip/hip_runtime.h>

#define NXI 384
#define NG  (NXI*NXI)          // 147456 elements per system
#define NSYS 8
#define BPS 32                 // blocks per system
#define NBLK (NSYS*BPS)        // 256 blocks
#define NTHR 256
#define ROWS_PB 12             // rows per block (384/32)
#define EPB (ROWS_PB*NXI)      // 4608 elements per block
#define EPT (EPB/NTHR)         // 18 elements per thread

// thr = EPS*NX*NY = 1e-9*147456
#define THRC 1.47456e-4f

// ---- relaxed agent-scope (fabric-coherent, cache-bypassing) accessors ----
__device__ __forceinline__ float aloadf(const float* p) {
  return __hip_atomic_load(p, __ATOMIC_RELAXED, __HIP_MEMORY_SCOPE_AGENT);
}
__device__ __forceinline__ void astoref(float* p, float v) {
  __hip_atomic_store(p, v, __ATOMIC_RELAXED, __HIP_MEMORY_SCOPE_AGENT);
}
__device__ __forceinline__ double aloadd(const double* p) {
  return __hip_atomic_load(p, __ATOMIC_RELAXED, __HIP_MEMORY_SCOPE_AGENT);
}
__device__ __forceinline__ void astored(double* p, double v) {
  __hip_atomic_store(p, v, __ATOMIC_RELAXED, __HIP_MEMORY_SCOPE_AGENT);
}

__device__ __forceinline__ double wave_red(double v) {
#pragma unroll
  for (int off = 32; off > 0; off >>= 1) v += __shfl_down(v, off, 64);
  return v;
}

// ---- per-system barrier: 32 blocks, one counter line, no scoped fences ----
// Every wave drains its own memory ops (s_waitcnt 0) before the block syncs,
// so the leader's arrival atomic strictly follows all of the block's agent
// stores (construction validated rounds 2-4).
__device__ __forceinline__ void sys_bar(unsigned* sbar, unsigned* phase, int tid) {
  __atomic_signal_fence(__ATOMIC_SEQ_CST);
  __builtin_amdgcn_s_waitcnt(0);
  __syncthreads();
  if (tid == 0) {
    const unsigned ph = ++(*phase);
    __hip_atomic_fetch_add(sbar, 1u, __ATOMIC_RELAXED, __HIP_MEMORY_SCOPE_AGENT);
    while (__hip_atomic_load(sbar, __ATOMIC_RELAXED, __HIP_MEMORY_SCOPE_AGENT) < ph * BPS) {
      __builtin_amdgcn_s_sleep(1);
    }
  } else {
    ++(*phase);
  }
  __syncthreads();
  __atomic_signal_fence(__ATOMIC_SEQ_CST);
}

// Block-reduce 3 doubles and agent-store to slot channels [chan0..chan0+2][sys][bs].
__device__ __forceinline__ void bred3(double v0, double v1, double v2,
                                      double* slots, int chan0,
                                      int sys, int bs, int tid) {
  __shared__ double sred[4][3];
  const int wid = tid >> 6, lane = tid & 63;
  const double w0 = wave_red(v0);
  const double w1 = wave_red(v1);
  const double w2 = wave_red(v2);
  if (lane == 0) { sred[wid][0] = w0; sred[wid][1] = w1; sred[wid][2] = w2; }
  __syncthreads();
  if (tid == 0) {
#pragma unroll
    for (int q = 0; q < 3; q++) {
      const double a = sred[0][q] + sred[1][q] + sred[2][q] + sred[3][q];
      astored(slots + (size_t)(chan0 + q) * NBLK + sys * BPS + bs, a);
    }
  }
  __syncthreads();
}

// Deterministic butterfly sum of one channel's 32 per-block partials; identical
// bit-exact result in every lane of every block of the system.
__device__ __forceinline__ double shred(const double* slots, int chan, int sys, int lane) {
  double v = aloadd(slots + (size_t)chan * NBLK + sys * BPS + (lane & 31));
  v += __shfl_xor(v, 1, 64);
  v += __shfl_xor(v, 2, 64);
  v += __shfl_xor(v, 4, 64);
  v += __shfl_xor(v, 8, 64);
  v += __shfl_xor(v, 16, 64);
  return v;
}

__device__ __forceinline__ float froguard(double sq) {
  return sq > 0.0 ? (float)sqrt(sq) : 0.0f;
}

// Publish one owned element into the LDS slab (+ global halo row if boundary).
__device__ __forceinline__ void publish(float val, int e, float* lds, float* hal) {
  const int lr = e / NXI, c = e - lr * NXI;
  lds[(lr + 1) * NXI + c] = val;
  if (e < NXI)             astoref(hal + c, val);              // own top row
  if (e >= EPB - NXI)      astoref(hal + NXI + c, val);        // own bottom row
}

// Pull neighbor blocks' boundary rows into LDS halo rows 0 and 13.
__device__ __forceinline__ void load_halo(float* lds, const float* ghalo_sys, int bs, int tid) {
  for (int c = tid; c < NXI; c += NTHR) {
    if (bs > 0)       lds[c] = aloadf(ghalo_sys + (size_t)(bs - 1) * 2 * NXI + NXI + c);
    if (bs < BPS - 1) lds[(ROWS_PB + 1) * NXI + c] = aloadf(ghalo_sys + (size_t)(bs + 1) * 2 * NXI + c);
  }
  __syncthreads();
}

// 5-point stencil, coeffs + neighbors all from LDS; uc = center (register).
__device__ __forceinline__ float applyA_lds(const float* lds, float uc, int e, int gr0,
                                            const float* boo, const float* bmo,
                                            const float* bom, const float* bop,
                                            const float* bpo) {
  const int lr = e / NXI, c = e - lr * NXI;
  const int gr = gr0 + lr;
  const float um = (gr == 0)       ? uc : lds[lr * NXI + c];
  const float ud = (gr == NXI - 1) ? uc : lds[(lr + 2) * NXI + c];
  const float ul = (c == 0)        ? uc : lds[(lr + 1) * NXI + c - 1];
  const float ur = (c == NXI - 1)  ? uc : lds[(lr + 1) * NXI + c + 1];
  return boo[e] * uc + bmo[e] * um + bom[e] * ul + bop[e] * ur + bpo[e] * ud;
}

__global__ __launch_bounds__(NTHR, 1) void bicg_kernel(
    const float* __restrict__ V, const float* __restrict__ M1, const float* __restrict__ M2,
    float* __restrict__ xout, float* __restrict__ wsf) {
  const int blk = blockIdx.x;
  const int sys = blk & (NSYS - 1);   // blk%8: system (also XCD-affinity heuristic, perf only)
  const int bs  = blk >> 3;           // slab index within system
  const int tid = threadIdx.x;
  const int lane = tid & 63;
  const int gr0 = bs * ROWS_PB;       // first global row of this block's slab

  // ---- LDS: exchange slab (21.5 KB) + coefficient slabs (92 KB) = 113.7 KB/CU
  __shared__ float lds[(ROWS_PB + 2) * NXI];
  __shared__ float cf[5][EPB];
  float* boos = cf[0]; float* bmos = cf[1]; float* boms = cf[2];
  float* bops = cf[3]; float* bpos = cf[4];

  // ---- workspace layout (control + halos only; ws is effectively L2-uncached) ----
  unsigned* bar  = (unsigned*)wsf + sys * 32;          // per-system counter line (memset 0)
  double* slots  = (double*)(wsf + 1024);              // 24 chans * 256 doubles
  float* ghalo   = wsf + 16384;                        // [sys][bs][2][384] p/s halos
  float* ghalo2  = ghalo + (size_t)NSYS * BPS * 2 * NXI; // x halos for restart

  unsigned bphase = 0;

  const size_t so = (size_t)sys * NG;
  const size_t bo = so + (size_t)bs * EPB;            // this block's slab base
  const float* Vb  = V  + so;
  const float* M1b = M1 + so;
  const float* M2b = M2 + so;
  float* xs = xout + bo;                               // final write-out only
  float* ghalo_sys = ghalo  + (size_t)sys * BPS * 2 * NXI;
  float* ghalo2_sys= ghalo2 + (size_t)sys * BPS * 2 * NXI;
  float* hal  = ghalo_sys  + (size_t)bs * 2 * NXI;     // own p/s halo rows
  float* hal2 = ghalo2_sys + (size_t)bs * 2 * NXI;     // own x halo rows

  // ---------- Phase 0: stencil coefficients (into LDS) + V-mean partial ----------
  double vsum = 0.0;
#pragma unroll
  for (int k = 0; k < EPT; k++) {
    const int e = tid + k * NTHR;
    const int idx = bs * EPB + e;                      // index within system
    vsum += (double)Vb[idx];
    const int i = (int)((unsigned)idx / (unsigned)NXI);
    const int j = idx - i * NXI;
    const int a0 = (i - 1 < 0) ? 0 : i - 1;
    const int a1 = i;
    const int a2 = (i + 1 > NXI - 1) ? NXI - 1 : i + 1;
    const int b0 = (j - 1 < 0) ? 0 : j - 1;
    const int b1 = j;
    const int b2 = (j + 1 > NXI - 1) ? NXI - 1 : j + 1;
    const float vc = Vb[b1 * NXI + a1] + 1.0f;
    const float vu = Vb[b1 * NXI + a0] + 1.0f;
    const float vd = Vb[b1 * NXI + a2] + 1.0f;
    const float vl = Vb[b0 * NXI + a1] + 1.0f;
    const float vr = Vb[b2 * NXI + a1] + 1.0f;
    const float D1A = M1b[b1 * NXI + a1] * ((vd - vc) / (0.5f * (vd + vc)));
    const float D1B = M1b[b1 * NXI + a0] * ((vc - vu) / (0.5f * (vc + vu)));
    const float D2A = M2b[b1 * NXI + a1] * ((vr - vc) / (0.5f * (vr + vc)));
    const float D2B = M2b[b0 * NXI + a1] * ((vc - vl) / (0.5f * (vc + vl)));
    boos[e] = 41.0f - 5.0f * (D1B - D1A) - 5.0f * (D2B - D2A);
    bpos[e] = -10.0f + 5.0f * D1A;
    bmos[e] = -10.0f - 5.0f * D1B;
    bops[e] = -10.0f + 5.0f * D2A;
    boms[e] = -10.0f - 5.0f * D2B;
  }
  bred3(vsum, 0.0, 0.0, slots, 0, sys, bs, tid);
  sys_bar(bar, &bphase, tid);  // S0a

  // ---------- Phase 0b: x=mb; p=r=r0=b-Ax (x const -> rowsum trick) ----------
  const float mb = (float)(shred(slots, 0, sys, lane) / (double)NG) + 1.0f;  // mean(V)+OFFSET
  float preg[EPT], rreg[EPT], r0reg[EPT], vreg[EPT], treg[EPT], xreg[EPT];
  double r0sq = 0.0;
#pragma unroll
  for (int k = 0; k < EPT; k++) {
    const int e = tid + k * NTHR;
    const float ax = (boos[e] + bmos[e] + boms[e] + bops[e] + bpos[e]) * mb;
    const float pn = mb - ax;
    xreg[k] = mb;
    publish(pn, e, lds, hal);
    preg[k] = pn; rreg[k] = pn; r0reg[k] = pn;
    r0sq += (double)pn * (double)pn;
  }
  bred3(r0sq, 0.0, 0.0, slots, 3, sys, bs, tid);
  sys_bar(bar, &bphase, tid);  // S0b (publishes p halos + r0sq)
  float r0_abs = froguard(shred(slots, 3, sys, lane));
  float r_abs = r0_abs;

  float alpha = 0.f, omega = 0.f, rho = 0.f;

  for (int it = 0; it < 30; ++it) {
    if (!(r_abs > THRC)) break;  // uniform within system

    // ---- Phase 1: v = A p ; reduce sigma=<v,r0>, vabs2=<v,v>, rho=<r,r0>
    load_halo(lds, ghalo_sys, bs, tid);   // p halos
    {
      double psig = 0, pvab = 0, prho = 0;
#pragma unroll
      for (int k = 0; k < EPT; k++) {
        const int e = tid + k * NTHR;
        const float vv = applyA_lds(lds, preg[k], e, gr0, boos, bmos, boms, bops, bpos);
        vreg[k] = vv;
        psig += (double)vv * (double)r0reg[k];
        pvab += (double)vv * (double)vv;
        prho += (double)rreg[k] * (double)r0reg[k];
      }
      bred3(psig, pvab, prho, slots, 6, sys, bs, tid);
    }
    sys_bar(bar, &bphase, tid);  // S1

    const float sigma = (float)shred(slots, 6, sys, lane);
    const float v_abs = froguard(shred(slots, 7, sys, lane));
    rho = (float)shred(slots, 8, sys, lane);
    const bool RES = (sigma <= 1e-9f * v_abs * r0_abs);  // uniform

    if (RES) {
      // restart: p = r = r0 = b - A x ; reduce <p,p>
      __syncthreads();  // phase-1 slab reads done before overwrite
#pragma unroll
      for (int k = 0; k < EPT; k++) {
        const int e = tid + k * NTHR;
        publish(xreg[k], e, lds, hal2);   // x -> slab + x-halo buffer
      }
      sys_bar(bar, &bphase, tid);  // SR1 (publish x halos)
      load_halo(lds, ghalo2_sys, bs, tid);
      float pnl[EPT];
#pragma unroll
      for (int k = 0; k < EPT; k++) {
        const int e = tid + k * NTHR;
        const float ax = applyA_lds(lds, xreg[k], e, gr0, boos, bmos, boms, bops, bpos);
        pnl[k] = mb - ax;
      }
      __syncthreads();  // all slab reads done before overwrite with p
      double pacc = 0;
#pragma unroll
      for (int k = 0; k < EPT; k++) {
        const int e = tid + k * NTHR;
        const float pn = pnl[k];
        publish(pn, e, lds, hal);
        preg[k] = pn; rreg[k] = pn; r0reg[k] = pn;
        pacc += (double)pn * (double)pn;
      }
      bred3(pacc, 0.0, 0.0, slots, 9, sys, bs, tid);
      sys_bar(bar, &bphase, tid);  // SR2 (publish p halos + <p,p>)
      r0_abs = froguard(shred(slots, 9, sys, lane));
      r_abs = r0_abs;
      continue;
    }

    // ---- Phase 2: s = r - alpha*v ; reduce <s,s>  (s -> slab + halos)
    alpha = rho / sigma;
    __syncthreads();  // phase-1 slab reads done before overwrite
    {
      double pacc = 0;
#pragma unroll
      for (int k = 0; k < EPT; k++) {
        const int e = tid + k * NTHR;
        const float sv = rreg[k] - alpha * vreg[k];
        publish(sv, e, lds, hal);
        pacc += (double)sv * (double)sv;
      }
      bred3(pacc, 0.0, 0.0, slots, 9, sys, bs, tid);
    }
    sys_bar(bar, &bphase, tid);  // S2

    const float s_abs = froguard(shred(slots, 9, sys, lane));
    if (s_abs <= THRC) {
      // C3: x += alpha*p ; r = s (terminal: loop breaks at top)
#pragma unroll
      for (int k = 0; k < EPT; k++) {
        xreg[k] = xreg[k] + alpha * preg[k];
        rreg[k] = rreg[k] - alpha * vreg[k];
      }
      r_abs = s_abs;
      continue;
    }

    // ---- Phase 3: t = A s ; reduce <t,t>, <t,s>
    load_halo(lds, ghalo_sys, bs, tid);   // s halos
    {
      double ptt = 0, pts = 0;
#pragma unroll
      for (int k = 0; k < EPT; k++) {
        const int e = tid + k * NTHR;
        const float sc = rreg[k] - alpha * vreg[k];
        const float tv = applyA_lds(lds, sc, e, gr0, boos, bmos, boms, bops, bpos);
        treg[k] = tv;
        ptt += (double)tv * (double)tv;
        pts += (double)tv * (double)sc;
      }
      bred3(ptt, pts, 0.0, slots, 12, sys, bs, tid);
    }
    sys_bar(bar, &bphase, tid);  // S3

    // ---- Phase 4: omega; x += alpha*p + omega*s ; r = s - omega*t ; <r,r>, <r,r0>
    {
      const float tt  = (float)shred(slots, 12, sys, lane);
      const float tsv = (float)shred(slots, 13, sys, lane);
      omega = tsv / tt;
      double prr = 0, prh = 0;
#pragma unroll
      for (int k = 0; k < EPT; k++) {
        const float sc = rreg[k] - alpha * vreg[k];
        xreg[k] = xreg[k] + alpha * preg[k] + omega * sc;
        const float rn = sc - omega * treg[k];
        rreg[k] = rn;
        prr += (double)rn * (double)rn;
        prh += (double)rn * (double)r0reg[k];
      }
      bred3(prr, prh, 0.0, slots, 15, sys, bs, tid);
    }
    sys_bar(bar, &bphase, tid);  // S4

    // ---- Phase 5: beta; p = r + beta*(p - omega*v)  (p -> slab + halos)
    __syncthreads();  // phase-3 slab reads complete (S3/S4 passed); cheap safety
    {
      const float rr_abs  = froguard(shred(slots, 15, sys, lane));
      const float rho_new = (float)shred(slots, 16, sys, lane);
      const float beta = (alpha / omega) * (rho_new / rho);  // den == old rho
#pragma unroll
      for (int k = 0; k < EPT; k++) {
        const int e = tid + k * NTHR;
        const float pn = rreg[k] + beta * (preg[k] - omega * vreg[k]);
        preg[k] = pn;
        publish(pn, e, lds, hal);
      }
      r_abs = rr_abs;
    }
    sys_bar(bar, &bphase, tid);  // S5 (publish p halos before next matvec)
  }

  // final write-out of x (plain stores; end-of-kernel release makes host-visible)
#pragma unroll
  for (int k = 0; k < EPT; k++) {
    const int e = tid + k * NTHR;
    xs[e] = xreg[k];
  }
}

extern "C" void kernel_launch(void* const* d_in, const int* in_sizes, int n_in,
                              void* d_out, int out_size, void* d_ws, size_t ws_size,
                              hipStream_t stream) {
  const float* V  = (const float*)d_in[0];
  const float* M1 = (const float*)d_in[1];
  const float* M2 = (const float*)d_in[2];
  float* xout = (float*)d_out;
  float* wsf  = (float*)d_ws;
  // zero the 8 per-system barrier counter lines (ws is re-poisoned each call)
  hipMemsetAsync(d_ws, 0, 4096, stream);
  bicg_kernel<<<dim3(NBLK), dim3(NTHR), 0, stream>>>(V, M1, M2, xout, wsf);
}

// Round 6
// 681.685 us; speedup vs baseline: 8.7512x; 1.0750x over previous
//
#include <hip/hip_runtime.h>

#define NXI 384
#define NG  (NXI*NXI)          // 147456 elements per system
#define NSYS 8
#define BPS 32                 // blocks per system
#define NBLK (NSYS*BPS)        // 256 blocks
#define NTHR 256
#define ROWS_PB 12             // rows per block
#define EPB (ROWS_PB*NXI)      // 4608 elements per block
#define EPT (EPB/NTHR)         // 18 elements per thread

// thr = EPS*NX*NY = 1e-9*147456
#define THRC 1.47456e-4f

// ---- relaxed agent-scope (fabric-coherent, cache-bypassing) accessors ----
__device__ __forceinline__ float aloadf(const float* p) {
  return __hip_atomic_load(p, __ATOMIC_RELAXED, __HIP_MEMORY_SCOPE_AGENT);
}
__device__ __forceinline__ void astoref(float* p, float v) {
  __hip_atomic_store(p, v, __ATOMIC_RELAXED, __HIP_MEMORY_SCOPE_AGENT);
}
__device__ __forceinline__ double aloadd(const double* p) {
  return __hip_atomic_load(p, __ATOMIC_RELAXED, __HIP_MEMORY_SCOPE_AGENT);
}
__device__ __forceinline__ void astored(double* p, double v) {
  __hip_atomic_store(p, v, __ATOMIC_RELAXED, __HIP_MEMORY_SCOPE_AGENT);
}

__device__ __forceinline__ double wave_red(double v) {
#pragma unroll
  for (int off = 32; off > 0; off >>= 1) v += __shfl_down(v, off, 64);
  return v;
}

// ---- per-system barrier: 32 blocks, one counter line, no scoped fences ----
// (construction validated rounds 2-5)
__device__ __forceinline__ void sys_bar(unsigned* sbar, unsigned* phase, int tid) {
  __atomic_signal_fence(__ATOMIC_SEQ_CST);
  __builtin_amdgcn_s_waitcnt(0);
  __syncthreads();
  if (tid == 0) {
    const unsigned ph = ++(*phase);
    __hip_atomic_fetch_add(sbar, 1u, __ATOMIC_RELAXED, __HIP_MEMORY_SCOPE_AGENT);
    while (__hip_atomic_load(sbar, __ATOMIC_RELAXED, __HIP_MEMORY_SCOPE_AGENT) < ph * BPS) {
      __builtin_amdgcn_s_sleep(1);
    }
  } else {
    ++(*phase);
  }
  __syncthreads();
  __atomic_signal_fence(__ATOMIC_SEQ_CST);
}

// Block-reduce n<=5 doubles and agent-store to slot channels [chan0..chan0+n-1][sys][bs].
__device__ __forceinline__ void bredN(const double* v, int n,
                                      double* slots, int chan0,
                                      int sys, int bs, int tid) {
  __shared__ double sred[4][5];
  const int wid = tid >> 6, lane = tid & 63;
  for (int q = 0; q < n; q++) {
    const double w = wave_red(v[q]);
    if (lane == 0) sred[wid][q] = w;
  }
  __syncthreads();
  if (tid == 0) {
    for (int q = 0; q < n; q++) {
      const double a = sred[0][q] + sred[1][q] + sred[2][q] + sred[3][q];
      astored(slots + (size_t)(chan0 + q) * NBLK + sys * BPS + bs, a);
    }
  }
  __syncthreads();
}

// Deterministic butterfly sum of one channel's 32 per-block partials; bit-exact
// identical result in every lane of every block of the system.
__device__ __forceinline__ double shred(const double* slots, int chan, int sys, int lane) {
  double v = aloadd(slots + (size_t)chan * NBLK + sys * BPS + (lane & 31));
  v += __shfl_xor(v, 1, 64);
  v += __shfl_xor(v, 2, 64);
  v += __shfl_xor(v, 4, 64);
  v += __shfl_xor(v, 8, 64);
  v += __shfl_xor(v, 16, 64);
  return v;
}

__device__ __forceinline__ float froguard(double sq) {
  return sq > 0.0 ? (float)sqrt(sq) : 0.0f;
}

__global__ __launch_bounds__(NTHR, 1) void bicg_kernel(
    const float* __restrict__ V, const float* __restrict__ M1, const float* __restrict__ M2,
    float* __restrict__ xout, float* __restrict__ wsf) {
  const int blk = blockIdx.x;
  const int sys = blk & (NSYS - 1);   // blk%8: system (XCD-affinity heuristic, perf only)
  const int bs  = blk >> 3;           // slab index within system
  const int tid = threadIdx.x;
  const int lane = tid & 63;
  const int gr0 = bs * ROWS_PB;       // first global row of this block's slab

  // ---- LDS: 16-row exchange slab (rows -2..13), coeffs rows -1..12, halo bufs
  __shared__ float slab[16 * NXI];        // 24.6 KB; row r -> index (r+2)*NXI
  __shared__ float cf[5][14 * NXI];       // 107.5 KB; row r -> (r+1)*NXI
  __shared__ float rhal[2 * NXI];         // ghost r: [0..NXI)=row -1, [NXI..)=row 12
  __shared__ float vghal[2 * NXI];        // ghost v, same mapping
  float* cboo = cf[0]; float* cbmo = cf[1]; float* cbom = cf[2];
  float* cbop = cf[3]; float* cbpo = cf[4];

  // ---- workspace (control + halos only; ws is effectively uncached) ----
  unsigned* bar = (unsigned*)wsf + sys * 32;        // per-system counter line (memset 0)
  double* slots = (double*)(wsf + 1024);            // 11 chans * 256 doubles
  float* ghp_all = wsf + 16384;                     // byte 64KB: [sys][bs][4][NXI] p halos
  float* ghr_all = ghp_all + (size_t)NSYS * BPS * 4 * NXI;  // [sys][bs][2][NXI] r halos
  float* ghx_all = ghr_all + (size_t)NSYS * BPS * 2 * NXI;  // [sys][bs][2][NXI] x halos
  float* ghp = ghp_all + (size_t)sys * BPS * 4 * NXI;
  float* ghr = ghr_all + (size_t)sys * BPS * 2 * NXI;
  float* ghx = ghx_all + (size_t)sys * BPS * 2 * NXI;
  float* ghp_own = ghp + (size_t)bs * 4 * NXI;      // [0]=row0 [1]=row1 [2]=row10 [3]=row11
  float* ghr_own = ghr + (size_t)bs * 2 * NXI;      // [0]=row0 [1]=row11
  float* ghx_own = ghx + (size_t)bs * 2 * NXI;

  unsigned bphase = 0;

  const size_t so = (size_t)sys * NG;
  const float* Vb  = V  + so;
  const float* M1b = M1 + so;
  const float* M2b = M2 + so;
  float* xs = xout + so + (size_t)bs * EPB;          // final write-out only

  // ---------- Phase 0: coeffs for rows -1..12 (LDS) + V-mean partial ----------
  for (int q = tid; q < 14 * NXI; q += NTHR) {
    const int lr2 = q / NXI - 1;
    const int gr = gr0 + lr2;
    if ((unsigned)gr >= (unsigned)NXI) continue;     // nonexistent ghost rows
    const int j = q - (lr2 + 1) * NXI;
    const int i = gr;
    const int a0 = (i - 1 < 0) ? 0 : i - 1;
    const int a1 = i;
    const int a2 = (i + 1 > NXI - 1) ? NXI - 1 : i + 1;
    const int b0 = (j - 1 < 0) ? 0 : j - 1;
    const int b1 = j;
    const int b2 = (j + 1 > NXI - 1) ? NXI - 1 : j + 1;
    const float vc = Vb[b1 * NXI + a1] + 1.0f;
    const float vu = Vb[b1 * NXI + a0] + 1.0f;
    const float vd = Vb[b1 * NXI + a2] + 1.0f;
    const float vl = Vb[b0 * NXI + a1] + 1.0f;
    const float vr = Vb[b2 * NXI + a1] + 1.0f;
    const float D1A = M1b[b1 * NXI + a1] * ((vd - vc) / (0.5f * (vd + vc)));
    const float D1B = M1b[b1 * NXI + a0] * ((vc - vu) / (0.5f * (vc + vu)));
    const float D2A = M2b[b1 * NXI + a1] * ((vr - vc) / (0.5f * (vr + vc)));
    const float D2B = M2b[b0 * NXI + a1] * ((vc - vl) / (0.5f * (vc + vl)));
    cboo[q] = 41.0f - 5.0f * (D1B - D1A) - 5.0f * (D2B - D2A);
    cbpo[q] = -10.0f + 5.0f * D1A;
    cbmo[q] = -10.0f - 5.0f * D1B;
    cbop[q] = -10.0f + 5.0f * D2A;
    cbom[q] = -10.0f - 5.0f * D2B;
  }
  {
    double vsum = 0.0;
#pragma unroll
    for (int k = 0; k < EPT; k++) vsum += (double)Vb[bs * EPB + tid + k * NTHR];
    double d0[1] = {vsum};
    bredN(d0, 1, slots, 9, sys, bs, tid);
  }
  sys_bar(bar, &bphase, tid);  // S0a

  // ---------- Phase 0b: x=mb; p=r=r0=b-Ax (x const -> rowsum trick) ----------
  const float mb = (float)(shred(slots, 9, sys, lane) / (double)NG) + 1.0f;  // mean(V)+OFFSET
  float preg[EPT], rreg[EPT], r0reg[EPT], vreg[EPT], treg[EPT], xreg[EPT];
  {
    double r0sq = 0.0;
#pragma unroll
    for (int k = 0; k < EPT; k++) {
      const int e = tid + k * NTHR;
      const int ce = e + NXI;
      const float ax = (cboo[ce] + cbmo[ce] + cbom[ce] + cbop[ce] + cbpo[ce]) * mb;
      const float pn = mb - ax;
      xreg[k] = mb;
      preg[k] = pn; rreg[k] = pn; r0reg[k] = pn;
      slab[e + 2 * NXI] = pn;
      const int lr = e / NXI, c = e - lr * NXI;
      if (lr < 2)   astoref(ghp_own + lr * NXI + c, pn);
      if (lr >= 10) astoref(ghp_own + (lr - 8) * NXI + c, pn);
      if (lr == 0)  astoref(ghr_own + c, pn);
      if (lr == 11) astoref(ghr_own + NXI + c, pn);
      r0sq += (double)pn * (double)pn;
    }
    double d0[1] = {r0sq};
    bredN(d0, 1, slots, 10, sys, bs, tid);
  }
  sys_bar(bar, &bphase, tid);  // S0b (p halos + r halos + r0sq published)
  float r0_abs = froguard(shred(slots, 10, sys, lane));
  float r_abs = r0_abs;

  float alpha = 0.f, omega = 0.f, rho = 0.f;

  for (int it = 0; it < 30; ++it) {
    if (!(r_abs > THRC)) break;  // uniform within system

    // ==== P1: load halos; v = A p on own rows + 1 ghost row/side; 5 dots ====
    for (int c = tid; c < NXI; c += NTHR) {
      if (bs > 0) {
        const float* nb = ghp + (size_t)(bs - 1) * 4 * NXI;
        slab[c]       = aloadf(nb + 2 * NXI + c);   // p row gr0-2
        slab[NXI + c] = aloadf(nb + 3 * NXI + c);   // p row gr0-1
        rhal[c]       = aloadf(ghr + (size_t)(bs - 1) * 2 * NXI + NXI + c);
      }
      if (bs < BPS - 1) {
        const float* nb = ghp + (size_t)(bs + 1) * 4 * NXI;
        slab[14 * NXI + c] = aloadf(nb + c);        // p row gr0+12
        slab[15 * NXI + c] = aloadf(nb + NXI + c);  // p row gr0+13
        rhal[NXI + c]      = aloadf(ghr + (size_t)(bs + 1) * 2 * NXI + c);
      }
    }
    __syncthreads();
    // ghost v (rows gr0-1 and gr0+12; never row-clamped, column-clamp only)
    for (int g = tid; g < 2 * NXI; g += NTHR) {
      const bool top = g < NXI;
      const bool ok = top ? (bs > 0) : (bs < BPS - 1);
      if (ok) {
        const int c = top ? g : g - NXI;
        const int ce = top ? c : 13 * NXI + c;
        const int si = ce + NXI;
        const float uc = slab[si];
        const float um = slab[si - NXI];
        const float ud = slab[si + NXI];
        const float ul = (c == 0)       ? uc : slab[si - 1];
        const float ur = (c == NXI - 1) ? uc : slab[si + 1];
        vghal[g] = cboo[ce] * uc + cbmo[ce] * um + cbom[ce] * ul + cbop[ce] * ur + cbpo[ce] * ud;
      }
    }
    double ss2;  // set below; carried P2->P3
    {
      double d[5] = {0, 0, 0, 0, 0};
#pragma unroll
      for (int k = 0; k < EPT; k++) {
        const int e = tid + k * NTHR;
        const int lr = e / NXI, c = e - lr * NXI;
        const int gr = gr0 + lr;
        const int ce = e + NXI;
        const int si = e + 2 * NXI;
        const float uc = preg[k];
        const float um = (gr == 0)       ? uc : slab[si - NXI];
        const float ud = (gr == NXI - 1) ? uc : slab[si + NXI];
        const float ul = (c == 0)        ? uc : slab[si - 1];
        const float ur = (c == NXI - 1)  ? uc : slab[si + 1];
        const float vv = cboo[ce] * uc + cbmo[ce] * um + cbom[ce] * ul + cbop[ce] * ur + cbpo[ce] * ud;
        vreg[k] = vv;
        d[0] += (double)vv * (double)r0reg[k];   // sigma
        d[1] += (double)vv * (double)vv;         // <v,v>
        d[2] += (double)rreg[k] * (double)r0reg[k]; // rho
        d[3] += (double)rreg[k] * (double)vv;    // <r,v>
        d[4] += (double)rreg[k] * (double)rreg[k]; // <r,r>
      }
      bredN(d, 5, slots, 0, sys, bs, tid);
    }
    sys_bar(bar, &bphase, tid);  // B

    // ==== P2: scalars; restart / C3 / s (own+ghost) + t = A s + 4 dots ====
    const double sig_d = shred(slots, 0, sys, lane);
    const double vab_d = shred(slots, 1, sys, lane);
    const double rho_d = shred(slots, 2, sys, lane);
    const double rv_d  = shred(slots, 3, sys, lane);
    const double rr_d  = shred(slots, 4, sys, lane);
    const float sigma = (float)sig_d;
    const float v_abs = froguard(vab_d);
    rho = (float)rho_d;
    const bool RES = (sigma <= 1e-9f * v_abs * r0_abs);  // uniform

    if (RES) {
      // restart: p = r = r0 = b - A x ; reduce <p,p>
#pragma unroll
      for (int k = 0; k < EPT; k++) {
        const int e = tid + k * NTHR;
        slab[e + 2 * NXI] = xreg[k];
        const int lr = e / NXI, c = e - lr * NXI;
        if (lr == 0)  astoref(ghx_own + c, xreg[k]);
        if (lr == 11) astoref(ghx_own + NXI + c, xreg[k]);
      }
      sys_bar(bar, &bphase, tid);  // R1 (x slab + 1-row x halos)
      for (int c = tid; c < NXI; c += NTHR) {
        if (bs > 0)       slab[NXI + c]      = aloadf(ghx + (size_t)(bs - 1) * 2 * NXI + NXI + c);
        if (bs < BPS - 1) slab[14 * NXI + c] = aloadf(ghx + (size_t)(bs + 1) * 2 * NXI + c);
      }
      __syncthreads();
#pragma unroll
      for (int k = 0; k < EPT; k++) {
        const int e = tid + k * NTHR;
        const int lr = e / NXI, c = e - lr * NXI;
        const int gr = gr0 + lr;
        const int ce = e + NXI;
        const int si = e + 2 * NXI;
        const float uc = xreg[k];
        const float um = (gr == 0)       ? uc : slab[si - NXI];
        const float ud = (gr == NXI - 1) ? uc : slab[si + NXI];
        const float ul = (c == 0)        ? uc : slab[si - 1];
        const float ur = (c == NXI - 1)  ? uc : slab[si + 1];
        treg[k] = mb - (cboo[ce] * uc + cbmo[ce] * um + cbom[ce] * ul + cbop[ce] * ur + cbpo[ce] * ud);
      }
      __syncthreads();  // all x reads done before overwriting slab with p
      {
        double pacc = 0;
#pragma unroll
        for (int k = 0; k < EPT; k++) {
          const int e = tid + k * NTHR;
          const float pn = treg[k];
          slab[e + 2 * NXI] = pn;
          preg[k] = pn; rreg[k] = pn; r0reg[k] = pn;
          const int lr = e / NXI, c = e - lr * NXI;
          if (lr < 2)   astoref(ghp_own + lr * NXI + c, pn);
          if (lr >= 10) astoref(ghp_own + (lr - 8) * NXI + c, pn);
          if (lr == 0)  astoref(ghr_own + c, pn);
          if (lr == 11) astoref(ghr_own + NXI + c, pn);
          pacc += (double)pn * (double)pn;
        }
        double d0[1] = {pacc};
        bredN(d0, 1, slots, 10, sys, bs, tid);
      }
      sys_bar(bar, &bphase, tid);  // R2 (p halos + r halos + <p,p>)
      r0_abs = froguard(shred(slots, 10, sys, lane));
      r_abs = r0_abs;
      continue;
    }

    alpha = rho / sigma;
    const double da = (double)alpha;
    ss2 = rr_d - 2.0 * da * rv_d + da * da * vab_d;   // <s,s> analytic
    const float s_abs = froguard(ss2);

    if (s_abs <= THRC) {
      // C3: x += alpha*p ; r = s (terminal: loop breaks at top)
#pragma unroll
      for (int k = 0; k < EPT; k++) {
        xreg[k] = xreg[k] + alpha * preg[k];
        rreg[k] = rreg[k] - alpha * vreg[k];
      }
      r_abs = s_abs;
      continue;
    }

    // s -> slab (own rows + 1 ghost row/side, locally computed)
#pragma unroll
    for (int k = 0; k < EPT; k++) {
      const int e = tid + k * NTHR;
      slab[e + 2 * NXI] = rreg[k] - alpha * vreg[k];
    }
    for (int g = tid; g < 2 * NXI; g += NTHR) {
      const bool top = g < NXI;
      const bool ok = top ? (bs > 0) : (bs < BPS - 1);
      if (ok) {
        const int c = top ? g : g - NXI;
        const int si = (top ? NXI : 14 * NXI) + c;
        slab[si] = rhal[g] - alpha * vghal[g];
      }
    }
    __syncthreads();
    {
      double d[4] = {0, 0, 0, 0};
#pragma unroll
      for (int k = 0; k < EPT; k++) {
        const int e = tid + k * NTHR;
        const int lr = e / NXI, c = e - lr * NXI;
        const int gr = gr0 + lr;
        const int ce = e + NXI;
        const int si = e + 2 * NXI;
        const float sc = rreg[k] - alpha * vreg[k];
        const float um = (gr == 0)       ? sc : slab[si - NXI];
        const float ud = (gr == NXI - 1) ? sc : slab[si + NXI];
        const float ul = (c == 0)        ? sc : slab[si - 1];
        const float ur = (c == NXI - 1)  ? sc : slab[si + 1];
        const float tv = cboo[ce] * sc + cbmo[ce] * um + cbom[ce] * ul + cbop[ce] * ur + cbpo[ce] * ud;
        treg[k] = tv;
        d[0] += (double)tv * (double)tv;          // <t,t>
        d[1] += (double)tv * (double)sc;          // <t,s>
        d[2] += (double)sc * (double)r0reg[k];    // <s,r0>
        d[3] += (double)tv * (double)r0reg[k];    // <t,r0>
      }
      bredN(d, 4, slots, 5, sys, bs, tid);
    }
    sys_bar(bar, &bphase, tid);  // C

    // ==== P3: omega/beta/r_abs analytic; update x, r, p; publish halos ====
    {
      const double tt_d  = shred(slots, 5, sys, lane);
      const double ts_d  = shred(slots, 6, sys, lane);
      const double sr0_d = shred(slots, 7, sys, lane);
      const double tr0_d = shred(slots, 8, sys, lane);
      omega = (float)ts_d / (float)tt_d;
      const double dw = (double)omega;
      const float rho_new = (float)(sr0_d - dw * tr0_d);
      const double rr_new = ss2 - 2.0 * dw * ts_d + dw * dw * tt_d;
      const float beta = (alpha / omega) * (rho_new / rho);
#pragma unroll
      for (int k = 0; k < EPT; k++) {
        const int e = tid + k * NTHR;
        const float sc = rreg[k] - alpha * vreg[k];
        xreg[k] = xreg[k] + alpha * preg[k] + omega * sc;
        const float rn = sc - omega * treg[k];
        const float pn = rn + beta * (preg[k] - omega * vreg[k]);
        rreg[k] = rn;
        preg[k] = pn;
        slab[e + 2 * NXI] = pn;
        const int lr = e / NXI, c = e - lr * NXI;
        if (lr < 2)   astoref(ghp_own + lr * NXI + c, pn);
        if (lr >= 10) astoref(ghp_own + (lr - 8) * NXI + c, pn);
        if (lr == 0)  astoref(ghr_own + c, rn);
        if (lr == 11) astoref(ghr_own + NXI + c, rn);
      }
      r_abs = froguard(rr_new);
    }
    sys_bar(bar, &bphase, tid);  // A (publish p/r halos before next matvec)
  }

  // final write-out of x (plain stores; end-of-kernel release makes host-visible)
#pragma unroll
  for (int k = 0; k < EPT; k++) {
    xs[tid + k * NTHR] = xreg[k];
  }
}

extern "C" void kernel_launch(void* const* d_in, const int* in_sizes, int n_in,
                              void* d_out, int out_size, void* d_ws, size_t ws_size,
                              hipStream_t stream) {
  const float* V  = (const float*)d_in[0];
  const float* M1 = (const float*)d_in[1];
  const float* M2 = (const float*)d_in[2];
  float* xout = (float*)d_out;
  float* wsf  = (float*)d_ws;
  // zero the 8 per-system barrier counter lines (ws is re-poisoned each call)
  hipMemsetAsync(d_ws, 0, 4096, stream);
  bicg_kernel<<<dim3(NBLK), dim3(NTHR), 0, stream>>>(V, M1, M2, xout, wsf);
}

// Round 7
// 623.265 us; speedup vs baseline: 9.5715x; 1.0937x over previous
//
#include <hip/hip_runtime.h>

#define NXI 384
#define NG  (NXI*NXI)          // 147456 elements per system
#define NSYS 8
#define BPS 32                 // blocks per system
#define NBLK (NSYS*BPS)        // 256 blocks
#define NTHR 512               // 8 waves/CU: latency hiding for LDS/VALU chains
#define ROWS_PB 12             // rows per block
#define EPB (ROWS_PB*NXI)      // 4608 elements per block
#define EPT (EPB/NTHR)         // 9 elements per thread

// thr = EPS*NX*NY = 1e-9*147456
#define THRC 1.47456e-4f

// ---- relaxed agent-scope (fabric-coherent, cache-bypassing) accessors ----
__device__ __forceinline__ float aloadf(const float* p) {
  return __hip_atomic_load(p, __ATOMIC_RELAXED, __HIP_MEMORY_SCOPE_AGENT);
}
__device__ __forceinline__ void astoref(float* p, float v) {
  __hip_atomic_store(p, v, __ATOMIC_RELAXED, __HIP_MEMORY_SCOPE_AGENT);
}
__device__ __forceinline__ double aloadd(const double* p) {
  return __hip_atomic_load(p, __ATOMIC_RELAXED, __HIP_MEMORY_SCOPE_AGENT);
}
__device__ __forceinline__ void astored(double* p, double v) {
  __hip_atomic_store(p, v, __ATOMIC_RELAXED, __HIP_MEMORY_SCOPE_AGENT);
}

__device__ __forceinline__ double wave_red(double v) {
#pragma unroll
  for (int off = 32; off > 0; off >>= 1) v += __shfl_down(v, off, 64);
  return v;
}

// ---- per-system flag barrier: contention-free (no RMW), fused arrival ----
// Each block owns one flag; arrival = plain UC store of the new phase number
// after all the block's stores have drained (per-wave s_waitcnt + syncthreads,
// same visibility construction validated rounds 2-6). Detection: wave 0 loads
// all 32 flags in parallel and ballots until every flag >= phase.
__device__ __forceinline__ void sys_bar(unsigned* flags, unsigned* phase, int tid, int bs) {
  __atomic_signal_fence(__ATOMIC_SEQ_CST);
  __builtin_amdgcn_s_waitcnt(0);   // drain this wave's outstanding stores
  __syncthreads();                 // => ALL waves' stores drained
  const unsigned ph = ++(*phase);
  if (tid == 0) {
    __hip_atomic_store(flags + bs, ph, __ATOMIC_RELAXED, __HIP_MEMORY_SCOPE_AGENT);
  }
  if (tid < 64) {
    while (true) {
      const unsigned f = __hip_atomic_load(flags + (tid & 31), __ATOMIC_RELAXED,
                                           __HIP_MEMORY_SCOPE_AGENT);
      if (__ballot(f >= ph) == ~0ull) break;
      __builtin_amdgcn_s_sleep(1);
    }
  }
  __syncthreads();
  __atomic_signal_fence(__ATOMIC_SEQ_CST);
}

// Block-reduce n<=5 doubles and agent-store to slot channels [chan0..chan0+n-1][sys][bs].
__device__ __forceinline__ void bredN(const double* v, int n,
                                      double* slots, int chan0,
                                      int sys, int bs, int tid) {
  __shared__ double sred[NTHR/64][5];
  const int wid = tid >> 6, lane = tid & 63;
  for (int q = 0; q < n; q++) {
    const double w = wave_red(v[q]);
    if (lane == 0) sred[wid][q] = w;
  }
  __syncthreads();
  if (tid == 0) {
    for (int q = 0; q < n; q++) {
      double a = 0.0;
#pragma unroll
      for (int w2 = 0; w2 < NTHR/64; w2++) a += sred[w2][q];
      astored(slots + (size_t)(chan0 + q) * NBLK + sys * BPS + bs, a);
    }
  }
  __syncthreads();
}

// Deterministic butterfly sum of one channel's 32 per-block partials; bit-exact
// identical result in every lane of every block of the system.
__device__ __forceinline__ double shred(const double* slots, int chan, int sys, int lane) {
  double v = aloadd(slots + (size_t)chan * NBLK + sys * BPS + (lane & 31));
  v += __shfl_xor(v, 1, 64);
  v += __shfl_xor(v, 2, 64);
  v += __shfl_xor(v, 4, 64);
  v += __shfl_xor(v, 8, 64);
  v += __shfl_xor(v, 16, 64);
  return v;
}

__device__ __forceinline__ float froguard(double sq) {
  return sq > 0.0 ? (float)sqrt(sq) : 0.0f;
}

__global__ __launch_bounds__(NTHR, 1) void bicg_kernel(
    const float* __restrict__ V, const float* __restrict__ M1, const float* __restrict__ M2,
    float* __restrict__ xout, float* __restrict__ wsf) {
  const int blk = blockIdx.x;
  const int sys = blk & (NSYS - 1);   // blk%8: system (XCD-affinity heuristic, perf only)
  const int bs  = blk >> 3;           // slab index within system
  const int tid = threadIdx.x;
  const int lane = tid & 63;
  const int gr0 = bs * ROWS_PB;       // first global row of this block's slab

  // ---- LDS: 16-row exchange slab (rows -2..13), coeffs rows -1..12, halo bufs
  __shared__ float slab[16 * NXI];        // 24.6 KB; row r -> index (r+2)*NXI
  __shared__ float cf[5][14 * NXI];       // 107.5 KB; row r -> (r+1)*NXI
  __shared__ float rhal[2 * NXI];         // ghost r: [0..NXI)=row -1, [NXI..)=row 12
  __shared__ float vghal[2 * NXI];        // ghost v, same mapping
  float* cboo = cf[0]; float* cbmo = cf[1]; float* cbom = cf[2];
  float* cbop = cf[3]; float* cbpo = cf[4];

  // ---- workspace (control + halos only; ws is effectively uncached) ----
  unsigned* flags = (unsigned*)wsf + sys * 32;      // per-system 32 flags (memset 0)
  double* slots = (double*)(wsf + 1024);            // 11 chans * 256 doubles
  float* ghp_all = wsf + 16384;                     // byte 64KB: [sys][bs][4][NXI] p halos
  float* ghr_all = ghp_all + (size_t)NSYS * BPS * 4 * NXI;  // [sys][bs][2][NXI] r halos
  float* ghx_all = ghr_all + (size_t)NSYS * BPS * 2 * NXI;  // [sys][bs][2][NXI] x halos
  float* ghp = ghp_all + (size_t)sys * BPS * 4 * NXI;
  float* ghr = ghr_all + (size_t)sys * BPS * 2 * NXI;
  float* ghx = ghx_all + (size_t)sys * BPS * 2 * NXI;
  float* ghp_own = ghp + (size_t)bs * 4 * NXI;      // [0]=row0 [1]=row1 [2]=row10 [3]=row11
  float* ghr_own = ghr + (size_t)bs * 2 * NXI;      // [0]=row0 [1]=row11
  float* ghx_own = ghx + (size_t)bs * 2 * NXI;

  unsigned bphase = 0;

  const size_t so = (size_t)sys * NG;
  const float* Vb  = V  + so;
  const float* M1b = M1 + so;
  const float* M2b = M2 + so;
  float* xs = xout + so + (size_t)bs * EPB;          // final write-out only

  // ---------- Phase 0: coeffs for rows -1..12 (LDS) + V-mean partial ----------
  for (int q = tid; q < 14 * NXI; q += NTHR) {
    const int lr2 = q / NXI - 1;
    const int gr = gr0 + lr2;
    if ((unsigned)gr >= (unsigned)NXI) continue;     // nonexistent ghost rows
    const int j = q - (lr2 + 1) * NXI;
    const int i = gr;
    const int a0 = (i - 1 < 0) ? 0 : i - 1;
    const int a1 = i;
    const int a2 = (i + 1 > NXI - 1) ? NXI - 1 : i + 1;
    const int b0 = (j - 1 < 0) ? 0 : j - 1;
    const int b1 = j;
    const int b2 = (j + 1 > NXI - 1) ? NXI - 1 : j + 1;
    const float vc = Vb[b1 * NXI + a1] + 1.0f;
    const float vu = Vb[b1 * NXI + a0] + 1.0f;
    const float vd = Vb[b1 * NXI + a2] + 1.0f;
    const float vl = Vb[b0 * NXI + a1] + 1.0f;
    const float vr = Vb[b2 * NXI + a1] + 1.0f;
    const float D1A = M1b[b1 * NXI + a1] * ((vd - vc) / (0.5f * (vd + vc)));
    const float D1B = M1b[b1 * NXI + a0] * ((vc - vu) / (0.5f * (vc + vu)));
    const float D2A = M2b[b1 * NXI + a1] * ((vr - vc) / (0.5f * (vr + vc)));
    const float D2B = M2b[b0 * NXI + a1] * ((vc - vl) / (0.5f * (vc + vl)));
    cboo[q] = 41.0f - 5.0f * (D1B - D1A) - 5.0f * (D2B - D2A);
    cbpo[q] = -10.0f + 5.0f * D1A;
    cbmo[q] = -10.0f - 5.0f * D1B;
    cbop[q] = -10.0f + 5.0f * D2A;
    cbom[q] = -10.0f - 5.0f * D2B;
  }
  {
    double vsum = 0.0;
#pragma unroll
    for (int k = 0; k < EPT; k++) vsum += (double)Vb[bs * EPB + tid + k * NTHR];
    double d0[1] = {vsum};
    bredN(d0, 1, slots, 9, sys, bs, tid);
  }
  sys_bar(flags, &bphase, tid, bs);  // S0a

  // ---------- Phase 0b: x=mb; p=r=r0=b-Ax (x const -> rowsum trick) ----------
  const float mb = (float)(shred(slots, 9, sys, lane) / (double)NG) + 1.0f;  // mean(V)+OFFSET
  float preg[EPT], rreg[EPT], r0reg[EPT], vreg[EPT], treg[EPT], xreg[EPT];
  {
    double r0sq = 0.0;
#pragma unroll
    for (int k = 0; k < EPT; k++) {
      const int e = tid + k * NTHR;
      const int ce = e + NXI;
      const float ax = (cboo[ce] + cbmo[ce] + cbom[ce] + cbop[ce] + cbpo[ce]) * mb;
      const float pn = mb - ax;
      xreg[k] = mb;
      preg[k] = pn; rreg[k] = pn; r0reg[k] = pn;
      slab[e + 2 * NXI] = pn;
      const int lr = e / NXI, c = e - lr * NXI;
      if (lr < 2)   astoref(ghp_own + lr * NXI + c, pn);
      if (lr >= 10) astoref(ghp_own + (lr - 8) * NXI + c, pn);
      if (lr == 0)  astoref(ghr_own + c, pn);
      if (lr == 11) astoref(ghr_own + NXI + c, pn);
      r0sq += (double)pn * (double)pn;
    }
    double d0[1] = {r0sq};
    bredN(d0, 1, slots, 10, sys, bs, tid);
  }
  sys_bar(flags, &bphase, tid, bs);  // S0b (p halos + r halos + r0sq published)
  float r0_abs = froguard(shred(slots, 10, sys, lane));
  float r_abs = r0_abs;

  float alpha = 0.f, omega = 0.f, rho = 0.f;

  for (int it = 0; it < 30; ++it) {
    if (!(r_abs > THRC)) break;  // uniform within system

    // ==== P1: load halos; v = A p on own rows + 1 ghost row/side; 5 dots ====
    for (int c = tid; c < NXI; c += NTHR) {
      if (bs > 0) {
        const float* nb = ghp + (size_t)(bs - 1) * 4 * NXI;
        slab[c]       = aloadf(nb + 2 * NXI + c);   // p row gr0-2
        slab[NXI + c] = aloadf(nb + 3 * NXI + c);   // p row gr0-1
        rhal[c]       = aloadf(ghr + (size_t)(bs - 1) * 2 * NXI + NXI + c);
      }
      if (bs < BPS - 1) {
        const float* nb = ghp + (size_t)(bs + 1) * 4 * NXI;
        slab[14 * NXI + c] = aloadf(nb + c);        // p row gr0+12
        slab[15 * NXI + c] = aloadf(nb + NXI + c);  // p row gr0+13
        rhal[NXI + c]      = aloadf(ghr + (size_t)(bs + 1) * 2 * NXI + c);
      }
    }
    __syncthreads();
    // ghost v (rows gr0-1 and gr0+12; never row-clamped, column-clamp only)
    for (int g = tid; g < 2 * NXI; g += NTHR) {
      const bool top = g < NXI;
      const bool ok = top ? (bs > 0) : (bs < BPS - 1);
      if (ok) {
        const int c = top ? g : g - NXI;
        const int ce = top ? c : 13 * NXI + c;
        const int si = ce + NXI;
        const float uc = slab[si];
        const float um = slab[si - NXI];
        const float ud = slab[si + NXI];
        const float ul = (c == 0)       ? uc : slab[si - 1];
        const float ur = (c == NXI - 1) ? uc : slab[si + 1];
        vghal[g] = cboo[ce] * uc + cbmo[ce] * um + cbom[ce] * ul + cbop[ce] * ur + cbpo[ce] * ud;
      }
    }
    double ss2;  // set below; carried P2->P3
    {
      double d[5] = {0, 0, 0, 0, 0};
#pragma unroll
      for (int k = 0; k < EPT; k++) {
        const int e = tid + k * NTHR;
        const int lr = e / NXI, c = e - lr * NXI;
        const int gr = gr0 + lr;
        const int ce = e + NXI;
        const int si = e + 2 * NXI;
        const float uc = preg[k];
        const float um = (gr == 0)       ? uc : slab[si - NXI];
        const float ud = (gr == NXI - 1) ? uc : slab[si + NXI];
        const float ul = (c == 0)        ? uc : slab[si - 1];
        const float ur = (c == NXI - 1)  ? uc : slab[si + 1];
        const float vv = cboo[ce] * uc + cbmo[ce] * um + cbom[ce] * ul + cbop[ce] * ur + cbpo[ce] * ud;
        vreg[k] = vv;
        d[0] += (double)vv * (double)r0reg[k];      // sigma
        d[1] += (double)vv * (double)vv;            // <v,v>
        d[2] += (double)rreg[k] * (double)r0reg[k]; // rho
        d[3] += (double)rreg[k] * (double)vv;       // <r,v>
        d[4] += (double)rreg[k] * (double)rreg[k];  // <r,r>
      }
      bredN(d, 5, slots, 0, sys, bs, tid);
    }
    sys_bar(flags, &bphase, tid, bs);  // B

    // ==== P2: scalars; restart / C3 / s (own+ghost) + t = A s + 4 dots ====
    const double sig_d = shred(slots, 0, sys, lane);
    const double vab_d = shred(slots, 1, sys, lane);
    const double rho_d = shred(slots, 2, sys, lane);
    const double rv_d  = shred(slots, 3, sys, lane);
    const double rr_d  = shred(slots, 4, sys, lane);
    const float sigma = (float)sig_d;
    const float v_abs = froguard(vab_d);
    rho = (float)rho_d;
    const bool RES = (sigma <= 1e-9f * v_abs * r0_abs);  // uniform

    if (RES) {
      // restart: p = r = r0 = b - A x ; reduce <p,p>
      __syncthreads();
#pragma unroll
      for (int k = 0; k < EPT; k++) {
        const int e = tid + k * NTHR;
        slab[e + 2 * NXI] = xreg[k];
        const int lr = e / NXI, c = e - lr * NXI;
        if (lr == 0)  astoref(ghx_own + c, xreg[k]);
        if (lr == 11) astoref(ghx_own + NXI + c, xreg[k]);
      }
      sys_bar(flags, &bphase, tid, bs);  // R1 (x slab + 1-row x halos)
      for (int c = tid; c < NXI; c += NTHR) {
        if (bs > 0)       slab[NXI + c]      = aloadf(ghx + (size_t)(bs - 1) * 2 * NXI + NXI + c);
        if (bs < BPS - 1) slab[14 * NXI + c] = aloadf(ghx + (size_t)(bs + 1) * 2 * NXI + c);
      }
      __syncthreads();
#pragma unroll
      for (int k = 0; k < EPT; k++) {
        const int e = tid + k * NTHR;
        const int lr = e / NXI, c = e - lr * NXI;
        const int gr = gr0 + lr;
        const int ce = e + NXI;
        const int si = e + 2 * NXI;
        const float uc = xreg[k];
        const float um = (gr == 0)       ? uc : slab[si - NXI];
        const float ud = (gr == NXI - 1) ? uc : slab[si + NXI];
        const float ul = (c == 0)        ? uc : slab[si - 1];
        const float ur = (c == NXI - 1)  ? uc : slab[si + 1];
        treg[k] = mb - (cboo[ce] * uc + cbmo[ce] * um + cbom[ce] * ul + cbop[ce] * ur + cbpo[ce] * ud);
      }
      __syncthreads();  // all x reads done before overwriting slab with p
      {
        double pacc = 0;
#pragma unroll
        for (int k = 0; k < EPT; k++) {
          const int e = tid + k * NTHR;
          const float pn = treg[k];
          slab[e + 2 * NXI] = pn;
          preg[k] = pn; rreg[k] = pn; r0reg[k] = pn;
          const int lr = e / NXI, c = e - lr * NXI;
          if (lr < 2)   astoref(ghp_own + lr * NXI + c, pn);
          if (lr >= 10) astoref(ghp_own + (lr - 8) * NXI + c, pn);
          if (lr == 0)  astoref(ghr_own + c, pn);
          if (lr == 11) astoref(ghr_own + NXI + c, pn);
          pacc += (double)pn * (double)pn;
        }
        double d0[1] = {pacc};
        bredN(d0, 1, slots, 10, sys, bs, tid);
      }
      sys_bar(flags, &bphase, tid, bs);  // R2 (p halos + r halos + <p,p>)
      r0_abs = froguard(shred(slots, 10, sys, lane));
      r_abs = r0_abs;
      continue;
    }

    alpha = rho / sigma;
    const double da = (double)alpha;
    ss2 = rr_d - 2.0 * da * rv_d + da * da * vab_d;   // <s,s> analytic
    const float s_abs = froguard(ss2);

    if (s_abs <= THRC) {
      // C3: x += alpha*p ; r = s (terminal: loop breaks at top)
#pragma unroll
      for (int k = 0; k < EPT; k++) {
        xreg[k] = xreg[k] + alpha * preg[k];
        rreg[k] = rreg[k] - alpha * vreg[k];
      }
      r_abs = s_abs;
      continue;
    }

    // s -> slab (own rows + 1 ghost row/side, locally computed)
    __syncthreads();  // P1 slab reads done before overwrite
#pragma unroll
    for (int k = 0; k < EPT; k++) {
      const int e = tid + k * NTHR;
      slab[e + 2 * NXI] = rreg[k] - alpha * vreg[k];
    }
    for (int g = tid; g < 2 * NXI; g += NTHR) {
      const bool top = g < NXI;
      const bool ok = top ? (bs > 0) : (bs < BPS - 1);
      if (ok) {
        const int c = top ? g : g - NXI;
        const int si = (top ? NXI : 14 * NXI) + c;
        slab[si] = rhal[g] - alpha * vghal[g];
      }
    }
    __syncthreads();
    {
      double d[4] = {0, 0, 0, 0};
#pragma unroll
      for (int k = 0; k < EPT; k++) {
        const int e = tid + k * NTHR;
        const int lr = e / NXI, c = e - lr * NXI;
        const int gr = gr0 + lr;
        const int ce = e + NXI;
        const int si = e + 2 * NXI;
        const float sc = rreg[k] - alpha * vreg[k];
        const float um = (gr == 0)       ? sc : slab[si - NXI];
        const float ud = (gr == NXI - 1) ? sc : slab[si + NXI];
        const float ul = (c == 0)        ? sc : slab[si - 1];
        const float ur = (c == NXI - 1)  ? sc : slab[si + 1];
        const float tv = cboo[ce] * sc + cbmo[ce] * um + cbom[ce] * ul + cbop[ce] * ur + cbpo[ce] * ud;
        treg[k] = tv;
        d[0] += (double)tv * (double)tv;          // <t,t>
        d[1] += (double)tv * (double)sc;          // <t,s>
        d[2] += (double)sc * (double)r0reg[k];    // <s,r0>
        d[3] += (double)tv * (double)r0reg[k];    // <t,r0>
      }
      bredN(d, 4, slots, 5, sys, bs, tid);
    }
    sys_bar(flags, &bphase, tid, bs);  // C

    // ==== P3: omega/beta/r_abs analytic; update x, r, p; publish halos ====
    {
      const double tt_d  = shred(slots, 5, sys, lane);
      const double ts_d  = shred(slots, 6, sys, lane);
      const double sr0_d = shred(slots, 7, sys, lane);
      const double tr0_d = shred(slots, 8, sys, lane);
      omega = (float)ts_d / (float)tt_d;
      const double dw = (double)omega;
      const float rho_new = (float)(sr0_d - dw * tr0_d);
      const double rr_new = ss2 - 2.0 * dw * ts_d + dw * dw * tt_d;
      const float beta = (alpha / omega) * (rho_new / rho);
      __syncthreads();  // P2 slab reads done before overwrite with p
#pragma unroll
      for (int k = 0; k < EPT; k++) {
        const int e = tid + k * NTHR;
        const float sc = rreg[k] - alpha * vreg[k];
        xreg[k] = xreg[k] + alpha * preg[k] + omega * sc;
        const float rn = sc - omega * treg[k];
        const float pn = rn + beta * (preg[k] - omega * vreg[k]);
        rreg[k] = rn;
        preg[k] = pn;
        slab[e + 2 * NXI] = pn;
        const int lr = e / NXI, c = e - lr * NXI;
        if (lr < 2)   astoref(ghp_own + lr * NXI + c, pn);
        if (lr >= 10) astoref(ghp_own + (lr - 8) * NXI + c, pn);
        if (lr == 0)  astoref(ghr_own + c, rn);
        if (lr == 11) astoref(ghr_own + NXI + c, rn);
      }
      r_abs = froguard(rr_new);
    }
    sys_bar(flags, &bphase, tid, bs);  // A (publish p/r halos before next matvec)
  }

  // final write-out of x (plain stores; end-of-kernel release makes host-visible)
#pragma unroll
  for (int k = 0; k < EPT; k++) {
    xs[tid + k * NTHR] = xreg[k];
  }
}

extern "C" void kernel_launch(void* const* d_in, const int* in_sizes, int n_in,
                              void* d_out, int out_size, void* d_ws, size_t ws_size,
                              hipStream_t stream) {
  const float* V  = (const float*)d_in[0];
  const float* M1 = (const float*)d_in[1];
  const float* M2 = (const float*)d_in[2];
  float* xout = (float*)d_out;
  float* wsf  = (float*)d_ws;
  // zero the per-system flag arrays (ws is re-poisoned each call)
  hipMemsetAsync(d_ws, 0, 4096, stream);
  bicg_kernel<<<dim3(NBLK), dim3(NTHR), 0, stream>>>(V, M1, M2, xout, wsf);
}

// Round 8
// 585.510 us; speedup vs baseline: 10.1887x; 1.0645x over previous
//
#include <hip/hip_runtime.h>

#define NXI 384
#define NG  (NXI*NXI)          // 147456 elements per system
#define NSYS 8
#define BPS 32                 // blocks per system
#define NBLK (NSYS*BPS)        // 256 blocks
#define NTHR 512               // 8 waves/CU
#define ROWS_PB 12             // rows per block
#define EPB (ROWS_PB*NXI)      // 4608 elements per block
#define EPT (EPB/NTHR)         // 9 elements per thread

// thr = EPS*NX*NY = 1e-9*147456
#define THRC 1.47456e-4f

// ---- relaxed agent-scope (fabric-coherent, cache-bypassing) accessors ----
__device__ __forceinline__ float aloadf(const float* p) {
  return __hip_atomic_load(p, __ATOMIC_RELAXED, __HIP_MEMORY_SCOPE_AGENT);
}
__device__ __forceinline__ void astoref(float* p, float v) {
  __hip_atomic_store(p, v, __ATOMIC_RELAXED, __HIP_MEMORY_SCOPE_AGENT);
}
__device__ __forceinline__ double aloadd(const double* p) {
  return __hip_atomic_load(p, __ATOMIC_RELAXED, __HIP_MEMORY_SCOPE_AGENT);
}
__device__ __forceinline__ void astored(double* p, double v) {
  __hip_atomic_store(p, v, __ATOMIC_RELAXED, __HIP_MEMORY_SCOPE_AGENT);
}

__device__ __forceinline__ double wave_red(double v) {
#pragma unroll
  for (int off = 32; off > 0; off >>= 1) v += __shfl_down(v, off, 64);
  return v;
}

// ---- per-system flag barrier: contention-free, no RMW (validated round 7) ----
__device__ __forceinline__ void sys_bar(unsigned* flags, unsigned* phase, int tid, int bs) {
  __atomic_signal_fence(__ATOMIC_SEQ_CST);
  __builtin_amdgcn_s_waitcnt(0);   // drain this wave's outstanding stores
  __syncthreads();                 // => ALL waves' stores drained
  const unsigned ph = ++(*phase);
  if (tid == 0) {
    __hip_atomic_store(flags + bs, ph, __ATOMIC_RELAXED, __HIP_MEMORY_SCOPE_AGENT);
  }
  if (tid < 64) {
    while (true) {
      const unsigned f = __hip_atomic_load(flags + (tid & 31), __ATOMIC_RELAXED,
                                           __HIP_MEMORY_SCOPE_AGENT);
      if (__ballot(f >= ph) == ~0ull) break;
      __builtin_amdgcn_s_sleep(1);
    }
  }
  __syncthreads();
  __atomic_signal_fence(__ATOMIC_SEQ_CST);
}

// Block-reduce n<=5 doubles, agent-store to slot channels [chan0..][sys][bs].
__device__ __forceinline__ void bredN(const double* v, int n,
                                      double* slots, int chan0,
                                      int sys, int bs, int tid) {
  __shared__ double sred[NTHR/64][5];
  const int wid = tid >> 6, lane = tid & 63;
  for (int q = 0; q < n; q++) {
    const double w = wave_red(v[q]);
    if (lane == 0) sred[wid][q] = w;
  }
  __syncthreads();
  if (tid == 0) {
    for (int q = 0; q < n; q++) {
      double a = 0.0;
#pragma unroll
      for (int w2 = 0; w2 < NTHR/64; w2++) a += sred[w2][q];
      astored(slots + (size_t)(chan0 + q) * NBLK + sys * BPS + bs, a);
    }
  }
  __syncthreads();
}

// Deterministic butterfly sum of one channel's 32 partials (bit-exact everywhere).
__device__ __forceinline__ double shred(const double* slots, int chan, int sys, int lane) {
  double v = aloadd(slots + (size_t)chan * NBLK + sys * BPS + (lane & 31));
  v += __shfl_xor(v, 1, 64);
  v += __shfl_xor(v, 2, 64);
  v += __shfl_xor(v, 4, 64);
  v += __shfl_xor(v, 8, 64);
  v += __shfl_xor(v, 16, 64);
  return v;
}

__device__ __forceinline__ float froguard(double sq) {
  return sq > 0.0 ? (float)sqrt(sq) : 0.0f;
}

__global__ __launch_bounds__(NTHR, 1) void bicg_kernel(
    const float* __restrict__ V, const float* __restrict__ M1, const float* __restrict__ M2,
    float* __restrict__ xout, float* __restrict__ wsf) {
  const int blk = blockIdx.x;
  const int sys = blk & (NSYS - 1);
  const int bs  = blk >> 3;
  const int tid = threadIdx.x;
  const int lane = tid & 63;
  const int gr0 = bs * ROWS_PB;

  // ---- LDS (total 160,064 B): rows -1..12 -> index (r+1)*NXI ----
  __shared__ float slabP[14 * NXI];   // p (own + 1 ghost row/side)
  __shared__ float slabS[14 * NXI];   // s (own + ghost); x during restart
  __shared__ float cf[5][14 * NXI];   // coeffs rows -1..12
  __shared__ float vgh[2 * NXI];      // received v ghosts: [0..NXI)=row -1, rest=row 12
  __shared__ float tgh[2 * NXI];      // received t ghosts
  __shared__ float rgh[2 * NXI];      // maintained r ghosts (recursive, bit-exact)
  float* cboo = cf[0]; float* cbmo = cf[1]; float* cbom = cf[2];
  float* cbop = cf[3]; float* cbpo = cf[4];

  // ---- workspace (control + boundary rows only) ----
  unsigned* flags = (unsigned*)wsf + sys * 32;      // memset 0 before launch
  double* slots = (double*)(wsf + 1024);            // 10 chans * 256 doubles
  float* ghv_all = wsf + 16384;                     // [sys][bs][2][NXI] v boundary
  float* ght_all = ghv_all + (size_t)NSYS * BPS * 2 * NXI;  // t boundary
  float* ghx_all = ght_all + (size_t)NSYS * BPS * 2 * NXI;  // x boundary (restart)
  float* ghq_all = ghx_all + (size_t)NSYS * BPS * 2 * NXI;  // p boundary (restart)
  float* ghv = ghv_all + (size_t)sys * BPS * 2 * NXI;
  float* ght = ght_all + (size_t)sys * BPS * 2 * NXI;
  float* ghx = ghx_all + (size_t)sys * BPS * 2 * NXI;
  float* ghq = ghq_all + (size_t)sys * BPS * 2 * NXI;
  float* ghv_own = ghv + (size_t)bs * 2 * NXI;      // [0]=row0, [NXI]=row11
  float* ght_own = ght + (size_t)bs * 2 * NXI;
  float* ghx_own = ghx + (size_t)bs * 2 * NXI;
  float* ghq_own = ghq + (size_t)bs * 2 * NXI;

  unsigned bphase = 0;

  const size_t so = (size_t)sys * NG;
  const float* Vb  = V  + so;
  const float* M1b = M1 + so;
  const float* M2b = M2 + so;
  float* xs = xout + so + (size_t)bs * EPB;

  // ---------- Phase 0: coeffs rows -1..12 (LDS) + V-mean partial ----------
  for (int q = tid; q < 14 * NXI; q += NTHR) {
    const int lr2 = q / NXI - 1;
    const int gr = gr0 + lr2;
    if ((unsigned)gr >= (unsigned)NXI) continue;
    const int j = q - (lr2 + 1) * NXI;
    const int i = gr;
    const int a0 = (i - 1 < 0) ? 0 : i - 1;
    const int a1 = i;
    const int a2 = (i + 1 > NXI - 1) ? NXI - 1 : i + 1;
    const int b0 = (j - 1 < 0) ? 0 : j - 1;
    const int b1 = j;
    const int b2 = (j + 1 > NXI - 1) ? NXI - 1 : j + 1;
    const float vc = Vb[b1 * NXI + a1] + 1.0f;
    const float vu = Vb[b1 * NXI + a0] + 1.0f;
    const float vd = Vb[b1 * NXI + a2] + 1.0f;
    const float vl = Vb[b0 * NXI + a1] + 1.0f;
    const float vr = Vb[b2 * NXI + a1] + 1.0f;
    const float D1A = M1b[b1 * NXI + a1] * ((vd - vc) / (0.5f * (vd + vc)));
    const float D1B = M1b[b1 * NXI + a0] * ((vc - vu) / (0.5f * (vc + vu)));
    const float D2A = M2b[b1 * NXI + a1] * ((vr - vc) / (0.5f * (vr + vc)));
    const float D2B = M2b[b0 * NXI + a1] * ((vc - vl) / (0.5f * (vc + vl)));
    cboo[q] = 41.0f - 5.0f * (D1B - D1A) - 5.0f * (D2B - D2A);
    cbpo[q] = -10.0f + 5.0f * D1A;
    cbmo[q] = -10.0f - 5.0f * D1B;
    cbop[q] = -10.0f + 5.0f * D2A;
    cbom[q] = -10.0f - 5.0f * D2B;
  }
  {
    double vsum = 0.0;
#pragma unroll
    for (int k = 0; k < EPT; k++) vsum += (double)Vb[bs * EPB + tid + k * NTHR];
    double d0[1] = {vsum};
    bredN(d0, 1, slots, 9, sys, bs, tid);
  }
  sys_bar(flags, &bphase, tid, bs);  // S0 (only setup barrier)

  // ---------- Init: x=mb; p=r=r0=b-Ax on own rows AND ghost rows (local) ----------
  const float mb = (float)(shred(slots, 9, sys, lane) / (double)NG) + 1.0f;
  float preg[EPT], rreg[EPT], r0reg[EPT], vreg[EPT], treg[EPT], xreg[EPT];
#pragma unroll
  for (int k = 0; k < EPT; k++) {
    const int e = tid + k * NTHR;
    const int ce = e + NXI;
    const float pn = mb - (cboo[ce] + cbmo[ce] + cbom[ce] + cbop[ce] + cbpo[ce]) * mb;
    xreg[k] = mb;
    preg[k] = pn; rreg[k] = pn; r0reg[k] = pn;
    slabP[ce] = pn;
  }
  for (int g = tid; g < 2 * NXI; g += NTHR) {
    const bool top = g < NXI;
    if (top ? (bs > 0) : (bs < BPS - 1)) {
      const int c = top ? g : g - NXI;
      const int ci = top ? c : 13 * NXI + c;     // row -1 / row 12 index
      const float pn = mb - (cboo[ci] + cbmo[ci] + cbom[ci] + cbop[ci] + cbpo[ci]) * mb;
      slabP[ci] = pn;
      rgh[g] = pn;
    }
  }
  float r0_abs = 0.f, r_abs = 1.0f;   // r_abs dummy>thr to enter it=0
  float alpha = 0.f, omega = 0.f, rho = 0.f;

  for (int it = 0; it < 30; ++it) {
    if (!(r_abs > THRC)) break;  // uniform within system
    __syncthreads();             // slabP writes (init / P3) visible block-wide

    // ==== P1: v = A p own rows; 5 dots; publish v boundary rows ====
    double ss2;
    {
      double d[5] = {0, 0, 0, 0, 0};
#pragma unroll
      for (int k = 0; k < EPT; k++) {
        const int e = tid + k * NTHR;
        const int lr = e / NXI, c = e - lr * NXI;
        const int gr = gr0 + lr;
        const int ce = e + NXI;
        const float uc = preg[k];
        const float um = (gr == 0)       ? uc : slabP[ce - NXI];
        const float ud = (gr == NXI - 1) ? uc : slabP[ce + NXI];
        const float ul = (c == 0)        ? uc : slabP[ce - 1];
        const float ur = (c == NXI - 1)  ? uc : slabP[ce + 1];
        const float vv = cboo[ce] * uc + cbmo[ce] * um + cbom[ce] * ul + cbop[ce] * ur + cbpo[ce] * ud;
        vreg[k] = vv;
        if (lr == 0)  astoref(ghv_own + c, vv);
        if (lr == 11) astoref(ghv_own + NXI + c, vv);
        d[0] += (double)vv * (double)r0reg[k];      // sigma
        d[1] += (double)vv * (double)vv;            // <v,v>
        d[2] += (double)rreg[k] * (double)r0reg[k]; // rho
        d[3] += (double)rreg[k] * (double)vv;       // <r,v>
        d[4] += (double)rreg[k] * (double)rreg[k];  // <r,r>
      }
      bredN(d, 5, slots, 0, sys, bs, tid);
    }
    sys_bar(flags, &bphase, tid, bs);  // B

    // ==== P2: receive v ghosts; scalars; restart / C3 / s + t = A s + 4 dots ====
    for (int g = tid; g < 2 * NXI; g += NTHR) {
      const bool top = g < NXI;
      if (top ? (bs > 0) : (bs < BPS - 1)) {
        const int c = top ? g : g - NXI;
        vgh[g] = top ? aloadf(ghv + (size_t)(bs - 1) * 2 * NXI + NXI + c)
                     : aloadf(ghv + (size_t)(bs + 1) * 2 * NXI + c);
      }
    }
    const double sig_d = shred(slots, 0, sys, lane);
    const double vab_d = shred(slots, 1, sys, lane);
    const double rho_d = shred(slots, 2, sys, lane);
    const double rv_d  = shred(slots, 3, sys, lane);
    const double rr_d  = shred(slots, 4, sys, lane);
    const float sigma = (float)sig_d;
    const float v_abs = froguard(vab_d);
    rho = (float)rho_d;
    if (it == 0) {
      r0_abs = froguard(rr_d);     // <r,r> == <r0,r0> at it 0
      r_abs = r0_abs;
      if (!(r_abs > THRC)) break;  // converged at init: x stays mb (uniform)
    }
    const bool RES = (sigma <= 1e-9f * v_abs * r0_abs);  // uniform

    if (RES) {
      // restart: p = r = r0 = b - A x (explicit 1-row halo exchanges)
      __syncthreads();
#pragma unroll
      for (int k = 0; k < EPT; k++) {
        const int e = tid + k * NTHR;
        slabS[e + NXI] = xreg[k];
        const int lr = e / NXI, c = e - lr * NXI;
        if (lr == 0)  astoref(ghx_own + c, xreg[k]);
        if (lr == 11) astoref(ghx_own + NXI + c, xreg[k]);
      }
      sys_bar(flags, &bphase, tid, bs);  // R1
      for (int g = tid; g < 2 * NXI; g += NTHR) {
        const bool top = g < NXI;
        if (top ? (bs > 0) : (bs < BPS - 1)) {
          const int c = top ? g : g - NXI;
          const int ci = top ? c : 13 * NXI + c;
          slabS[ci] = top ? aloadf(ghx + (size_t)(bs - 1) * 2 * NXI + NXI + c)
                          : aloadf(ghx + (size_t)(bs + 1) * 2 * NXI + c);
        }
      }
      __syncthreads();
      {
        double pacc = 0;
#pragma unroll
        for (int k = 0; k < EPT; k++) {
          const int e = tid + k * NTHR;
          const int lr = e / NXI, c = e - lr * NXI;
          const int gr = gr0 + lr;
          const int ce = e + NXI;
          const float uc = xreg[k];
          const float um = (gr == 0)       ? uc : slabS[ce - NXI];
          const float ud = (gr == NXI - 1) ? uc : slabS[ce + NXI];
          const float ul = (c == 0)        ? uc : slabS[ce - 1];
          const float ur = (c == NXI - 1)  ? uc : slabS[ce + 1];
          const float pn = mb - (cboo[ce] * uc + cbmo[ce] * um + cbom[ce] * ul + cbop[ce] * ur + cbpo[ce] * ud);
          preg[k] = pn; rreg[k] = pn; r0reg[k] = pn;
          slabP[ce] = pn;
          if (lr == 0)  astoref(ghq_own + c, pn);
          if (lr == 11) astoref(ghq_own + NXI + c, pn);
          pacc += (double)pn * (double)pn;
        }
        double d0[1] = {pacc};
        bredN(d0, 1, slots, 9, sys, bs, tid);
      }
      sys_bar(flags, &bphase, tid, bs);  // R2
      for (int g = tid; g < 2 * NXI; g += NTHR) {
        const bool top = g < NXI;
        if (top ? (bs > 0) : (bs < BPS - 1)) {
          const int c = top ? g : g - NXI;
          const int ci = top ? c : 13 * NXI + c;
          const float pn = top ? aloadf(ghq + (size_t)(bs - 1) * 2 * NXI + NXI + c)
                               : aloadf(ghq + (size_t)(bs + 1) * 2 * NXI + c);
          slabP[ci] = pn;
          rgh[g] = pn;
        }
      }
      r0_abs = froguard(shred(slots, 9, sys, lane));
      r_abs = r0_abs;
      continue;
    }

    alpha = rho / sigma;
    const double da = (double)alpha;
    ss2 = rr_d - 2.0 * da * rv_d + da * da * vab_d;   // <s,s> analytic
    const float s_abs = froguard(ss2);

    if (s_abs <= THRC) {
      // C3: x += alpha*p ; r = s (terminal: loop breaks at top)
#pragma unroll
      for (int k = 0; k < EPT; k++) {
        xreg[k] = xreg[k] + alpha * preg[k];
        rreg[k] = rreg[k] - alpha * vreg[k];
      }
      r_abs = s_abs;
      continue;
    }

    // s own rows -> slabS; s ghosts locally: sgh = rgh - alpha*vgh
    __syncthreads();  // previous slabS/slabP readers done (safety for slabS reuse)
#pragma unroll
    for (int k = 0; k < EPT; k++) {
      const int e = tid + k * NTHR;
      slabS[e + NXI] = rreg[k] - alpha * vreg[k];
    }
    for (int g = tid; g < 2 * NXI; g += NTHR) {
      const bool top = g < NXI;
      if (top ? (bs > 0) : (bs < BPS - 1)) {
        const int c = top ? g : g - NXI;
        const int ci = top ? c : 13 * NXI + c;
        slabS[ci] = rgh[g] - alpha * vgh[g];
      }
    }
    __syncthreads();
    {
      double d[4] = {0, 0, 0, 0};
#pragma unroll
      for (int k = 0; k < EPT; k++) {
        const int e = tid + k * NTHR;
        const int lr = e / NXI, c = e - lr * NXI;
        const int gr = gr0 + lr;
        const int ce = e + NXI;
        const float sc = rreg[k] - alpha * vreg[k];
        const float um = (gr == 0)       ? sc : slabS[ce - NXI];
        const float ud = (gr == NXI - 1) ? sc : slabS[ce + NXI];
        const float ul = (c == 0)        ? sc : slabS[ce - 1];
        const float ur = (c == NXI - 1)  ? sc : slabS[ce + 1];
        const float tv = cboo[ce] * sc + cbmo[ce] * um + cbom[ce] * ul + cbop[ce] * ur + cbpo[ce] * ud;
        treg[k] = tv;
        if (lr == 0)  astoref(ght_own + c, tv);
        if (lr == 11) astoref(ght_own + NXI + c, tv);
        d[0] += (double)tv * (double)tv;          // <t,t>
        d[1] += (double)tv * (double)sc;          // <t,s>
        d[2] += (double)sc * (double)r0reg[k];    // <s,r0>
        d[3] += (double)tv * (double)r0reg[k];    // <t,r0>
      }
      bredN(d, 4, slots, 5, sys, bs, tid);
    }
    sys_bar(flags, &bphase, tid, bs);  // C

    // ==== P3: receive t ghosts; scalars; update x,r,p own + ghost; NO barrier ====
    for (int g = tid; g < 2 * NXI; g += NTHR) {
      const bool top = g < NXI;
      if (top ? (bs > 0) : (bs < BPS - 1)) {
        const int c = top ? g : g - NXI;
        tgh[g] = top ? aloadf(ght + (size_t)(bs - 1) * 2 * NXI + NXI + c)
                     : aloadf(ght + (size_t)(bs + 1) * 2 * NXI + c);
      }
    }
    {
      const double tt_d  = shred(slots, 5, sys, lane);
      const double ts_d  = shred(slots, 6, sys, lane);
      const double sr0_d = shred(slots, 7, sys, lane);
      const double tr0_d = shred(slots, 8, sys, lane);
      omega = (float)ts_d / (float)tt_d;
      const double dw = (double)omega;
      const float rho_new = (float)(sr0_d - dw * tr0_d);
      const double rr_new = ss2 - 2.0 * dw * ts_d + dw * dw * tt_d;
      const float beta = (alpha / omega) * (rho_new / rho);
#pragma unroll
      for (int k = 0; k < EPT; k++) {
        const int e = tid + k * NTHR;
        const float sc = rreg[k] - alpha * vreg[k];
        xreg[k] = xreg[k] + alpha * preg[k] + omega * sc;
        const float rn = sc - omega * treg[k];
        const float pn = rn + beta * (preg[k] - omega * vreg[k]);
        rreg[k] = rn;
        preg[k] = pn;
        slabP[e + NXI] = pn;
      }
      // ghost maintenance: same formulas, received v/t, recursive r/p ghosts
      for (int g = tid; g < 2 * NXI; g += NTHR) {
        const bool top = g < NXI;
        if (top ? (bs > 0) : (bs < BPS - 1)) {
          const int c = top ? g : g - NXI;
          const int ci = top ? c : 13 * NXI + c;
          const float sg = slabS[ci];               // s ghost (computed in P2)
          const float rg_new = sg - omega * tgh[g];
          const float pg_old = slabP[ci];
          const float pg_new = rg_new + beta * (pg_old - omega * vgh[g]);
          rgh[g] = rg_new;
          slabP[ci] = pg_new;
        }
      }
      r_abs = froguard(rr_new);
    }
    // no barrier: next P1 reads only block-local slabP (loop-top __syncthreads)
  }

  // final write-out of x
#pragma unroll
  for (int k = 0; k < EPT; k++) {
    xs[tid + k * NTHR] = xreg[k];
  }
}

extern "C" void kernel_launch(void* const* d_in, const int* in_sizes, int n_in,
                              void* d_out, int out_size, void* d_ws, size_t ws_size,
                              hipStream_t stream) {
  const float* V  = (const float*)d_in[0];
  const float* M1 = (const float*)d_in[1];
  const float* M2 = (const float*)d_in[2];
  float* xout = (float*)d_out;
  float* wsf  = (float*)d_ws;
  // zero the per-system flag arrays (ws is re-poisoned each call)
  hipMemsetAsync(d_ws, 0, 4096, stream);
  bicg_kernel<<<dim3(NBLK), dim3(NTHR), 0, stream>>>(V, M1, M2, xout, wsf);
}